// Round 1
// baseline (250.273 us; speedup 1.0000x reference)
//
#include <hip/hip_runtime.h>
#include <hip/hip_bf16.h>

namespace {

constexpr int NB  = 16;      // batch
constexpr int NC  = 256;     // channels
constexpr int NHW = 16384;   // H*W
constexpr int NK  = 1024;    // samples per image (K)
constexpr int IGN = 255;
constexpr float INVT = 14.285714285714285714f;  // 1/0.07

typedef __attribute__((ext_vector_type(8))) short short8;
typedef __attribute__((ext_vector_type(4))) float f32x4;

// ---------------------------------------------------------------- kernel 1
// Stable-priority sampler: foreground (label != 0 && != 255) in raster order,
// then background (label == 0), remaining slots stay IGN.
__global__ __launch_bounds__(256) void pcl_sample(const int* __restrict__ labels,
                                                  int* __restrict__ sel_lab,
                                                  int* __restrict__ sel_idx) {
  const int b = blockIdx.x;
  const int t = threadIdx.x;
  const int* lab = labels + b * NHW;
  __shared__ int cfg_s[256], cbg_s[256];
  __shared__ int pfg_s[256], pbg_s[256];
  __shared__ int tot_fg;

  for (int k = t; k < NK; k += 256) {
    sel_lab[b * NK + k] = IGN;
    sel_idx[b * NK + k] = 0;
  }

  const int start = t * 64;
  int cfg = 0, cbg = 0;
  for (int i = 0; i < 64; ++i) {
    int L = lab[start + i];
    if (L == IGN) continue;
    if (L == 0) ++cbg; else ++cfg;
  }
  cfg_s[t] = cfg; cbg_s[t] = cbg;
  __syncthreads();
  if (t == 0) {
    int af = 0, ab = 0;
    for (int i = 0; i < 256; ++i) {
      pfg_s[i] = af; af += cfg_s[i];
      pbg_s[i] = ab; ab += cbg_s[i];
    }
    tot_fg = af;
  }
  __syncthreads();
  const int nfg = tot_fg;
  int rf  = pfg_s[t];
  int rbg = pbg_s[t];
  for (int i = 0; i < 64; ++i) {
    int p = start + i;
    int L = lab[p];
    if (L == IGN) continue;
    if (L == 0) {
      int slot = nfg + rbg;
      if (slot < NK) { sel_lab[b * NK + slot] = L; sel_idx[b * NK + slot] = p; }
      ++rbg;
    } else {
      if (rf < NK) { sel_lab[b * NK + rf] = L; sel_idx[b * NK + rf] = p; }
      ++rf;
    }
  }
}

// ---------------------------------------------------------------- kernel 2
// Gather features for sampled pixels, L2-normalize each row, store bf16.
__global__ __launch_bounds__(256) void pcl_gather(const float* __restrict__ feats,
                                                  const int* __restrict__ sel_lab,
                                                  const int* __restrict__ sel_idx,
                                                  __hip_bfloat16* __restrict__ SF) {
  const int bk = blockIdx.x;        // b*NK + k
  const int b  = bk >> 10;
  const int t  = threadIdx.x;       // channel
  const int lab = sel_lab[bk];
  float v = 0.f;
  if (lab != IGN) {
    int p = sel_idx[bk];
    v = feats[((size_t)(b * NC + t)) * NHW + p];
  }
  float s = v * v;
  s += __shfl_xor(s, 1);  s += __shfl_xor(s, 2);  s += __shfl_xor(s, 4);
  s += __shfl_xor(s, 8);  s += __shfl_xor(s, 16); s += __shfl_xor(s, 32);
  __shared__ float wsum[4];
  __shared__ float rnorm;
  if ((t & 63) == 0) wsum[t >> 6] = s;
  __syncthreads();
  if (t == 0) {
    float tot = wsum[0] + wsum[1] + wsum[2] + wsum[3];
    rnorm = 1.f / fmaxf(sqrtf(tot), 1e-12f);
  }
  __syncthreads();
  SF[(size_t)bk * NC + t] = __float2bfloat16(v * rnorm);
}

// ---------------------------------------------------------------- kernel 3
// Per (b, 64-row strip): two passes over all 2048 cols with 16x16x32 bf16
// MFMA. Pass 1: row max (unmasked) + online SN over negatives.
// Pass 2: positive terms. Writes per-block partial (num, den).
__global__ __launch_bounds__(256) void pcl_main(const unsigned short* __restrict__ SF,
                                                const int* __restrict__ sel_lab,
                                                float* __restrict__ partials) {
  const int rb = blockIdx.x;       // 0..31  (row strip)
  const int b  = blockIdx.y;       // 0..15
  const int b2 = (b + 1) & 15;
  const int t    = threadIdx.x;
  const int lane = t & 63;
  const int w    = t >> 6;         // wave id (4 waves)
  const int lg   = lane >> 4;      // 0..3
  const int lr   = lane & 15;      // 0..15

  __shared__ short rowF[64 * 256];   // 32 KB, XOR-swizzled 16B chunks
  __shared__ short colF[64 * 256];   // 32 KB
  __shared__ int rowLab[64];
  __shared__ int colLab[64];
  __shared__ float red[4][2];

  // ---- stage row features (once) ----
#pragma unroll
  for (int it = 0; it < 8; ++it) {
    int c = t + it * 256;
    int r = c >> 5, ch = c & 31;
    int g = rb * 64 + r;
    int img = (g < NK) ? b : b2;
    int sr = g & (NK - 1);
    short8 v = *(const short8*)(SF + ((size_t)(img * NK + sr)) * NC + ch * 8);
    *(short8*)(rowF + r * 256 + ((ch ^ (r & 7)) * 8)) = v;
  }
  if (t < 64) {
    int g = rb * 64 + t;
    rowLab[t] = sel_lab[((g < NK) ? b : b2) * NK + (g & (NK - 1))];
  }
  __syncthreads();

  // ---- preload A fragments for this wave's 16 rows (constant all tiles) ----
  short8 afrag[8];
  const int arow = 16 * w + lr;
#pragma unroll
  for (int ks = 0; ks < 8; ++ks) {
    int ch = ks * 4 + lg;
    afrag[ks] = *(const short8*)(rowF + arow * 256 + ((ch ^ (arow & 7)) * 8));
  }

  // ---- per-lane D-row info (rows 16w + 4*lg + i) ----
  int rlab[4], gr[4], grblk[4];
  bool rv[4];
#pragma unroll
  for (int i = 0; i < 4; ++i) {
    int rloc = 16 * w + 4 * lg + i;
    gr[i]    = rb * 64 + rloc;
    rlab[i]  = rowLab[rloc];
    rv[i]    = (rlab[i] != IGN);
    grblk[i] = (gr[i] < NK) ? 0 : 1;
  }

  auto stage_col = [&](int ct) {
#pragma unroll
    for (int it = 0; it < 8; ++it) {
      int c = t + it * 256;
      int r = c >> 5, ch = c & 31;
      int g = ct * 64 + r;
      int img = (g < NK) ? b : b2;
      int sr = g & (NK - 1);
      short8 v = *(const short8*)(SF + ((size_t)(img * NK + sr)) * NC + ch * 8);
      *(short8*)(colF + r * 256 + ((ch ^ (r & 7)) * 8)) = v;
    }
    if (t < 64) {
      int g = ct * 64 + t;
      colLab[t] = sel_lab[((g < NK) ? b : b2) * NK + (g & (NK - 1))];
    }
  };

  auto compute_tile = [&](f32x4* acc) {
#pragma unroll
    for (int ks = 0; ks < 8; ++ks) {
#pragma unroll
      for (int c2 = 0; c2 < 4; ++c2) {
        int brow = 16 * c2 + lr;
        int ch = ks * 4 + lg;
        short8 bf = *(const short8*)(colF + brow * 256 + ((ch ^ (brow & 7)) * 8));
        acc[c2] = __builtin_amdgcn_mfma_f32_16x16x32_bf16(afrag[ks], bf, acc[c2], 0, 0, 0);
      }
    }
  };

  float mrun[4], snl[4];
#pragma unroll
  for (int i = 0; i < 4; ++i) { mrun[i] = -1e30f; snl[i] = 0.f; }

  // ================= pass 1: row max + online SN =================
  for (int ct = 0; ct < 32; ++ct) {
    __syncthreads();
    stage_col(ct);
    __syncthreads();

    f32x4 acc[4] = {{0.f,0.f,0.f,0.f},{0.f,0.f,0.f,0.f},{0.f,0.f,0.f,0.f},{0.f,0.f,0.f,0.f}};
    compute_tile(acc);

    int clab[4]; bool cvl[4];
#pragma unroll
    for (int c2 = 0; c2 < 4; ++c2) { clab[c2] = colLab[16 * c2 + lr]; cvl[c2] = (clab[c2] != IGN); }
    const int ctblk = (ct < 16) ? 0 : 1;

#pragma unroll
    for (int i = 0; i < 4; ++i) {
      float l0 = acc[0][i] * INVT, l1 = acc[1][i] * INVT;
      float l2 = acc[2][i] * INVT, l3 = acc[3][i] * INVT;
      float tmax = fmaxf(fmaxf(l0, l1), fmaxf(l2, l3));   // unmasked max
      tmax = fmaxf(tmax, __shfl_xor(tmax, 1));
      tmax = fmaxf(tmax, __shfl_xor(tmax, 2));
      tmax = fmaxf(tmax, __shfl_xor(tmax, 4));
      tmax = fmaxf(tmax, __shfl_xor(tmax, 8));
      float mnew = fmaxf(mrun[i], tmax);
      float sc = __expf(mrun[i] - mnew);
      bool sb = (grblk[i] == ctblk);
      float lv[4] = {l0, l1, l2, l3};
      float add = 0.f;
#pragma unroll
      for (int c2 = 0; c2 < 4; ++c2) {
        bool neg = rv[i] && cvl[c2] && sb && (rlab[i] != clab[c2]);
        add += neg ? __expf(lv[c2] - mnew) : 0.f;
      }
      snl[i] = snl[i] * sc + add;
      mrun[i] = mnew;
    }
  }

  // reduce SN over the 16-lane group (replicated result) + fold in EPS
  float SN[4];
#pragma unroll
  for (int i = 0; i < 4; ++i) {
    float s = snl[i];
    s += __shfl_xor(s, 1); s += __shfl_xor(s, 2);
    s += __shfl_xor(s, 4); s += __shfl_xor(s, 8);
    SN[i] = s + 1e-8f;
  }

  float pp[4] = {0.f,0.f,0.f,0.f}, np[4] = {0.f,0.f,0.f,0.f};

  // ================= pass 2: positive terms =================
  for (int ct = 0; ct < 32; ++ct) {
    __syncthreads();
    stage_col(ct);
    __syncthreads();

    f32x4 acc[4] = {{0.f,0.f,0.f,0.f},{0.f,0.f,0.f,0.f},{0.f,0.f,0.f,0.f},{0.f,0.f,0.f,0.f}};
    compute_tile(acc);

    int clab[4]; bool cvl[4];
#pragma unroll
    for (int c2 = 0; c2 < 4; ++c2) { clab[c2] = colLab[16 * c2 + lr]; cvl[c2] = (clab[c2] != IGN); }

#pragma unroll
    for (int i = 0; i < 4; ++i) {
      float lv[4] = {acc[0][i] * INVT, acc[1][i] * INVT, acc[2][i] * INVT, acc[3][i] * INVT};
#pragma unroll
      for (int c2 = 0; c2 < 4; ++c2) {
        int gc = ct * 64 + 16 * c2 + lr;
        bool pos = rv[i] && cvl[c2] && (rlab[i] == clab[c2]) && (gr[i] != gc);
        if (pos) {
          float ls = lv[c2] - mrun[i];
          pp[i] += ls - __logf(__expf(ls) + SN[i]);
          np[i] += 1.f;
        }
      }
    }
  }

  // per-row reduce over 16-lane group, then per-block partial
  float cn = 0.f, cd = 0.f;
#pragma unroll
  for (int i = 0; i < 4; ++i) {
    float p = pp[i], n = np[i];
    p += __shfl_xor(p, 1); p += __shfl_xor(p, 2); p += __shfl_xor(p, 4); p += __shfl_xor(p, 8);
    n += __shfl_xor(n, 1); n += __shfl_xor(n, 2); n += __shfl_xor(n, 4); n += __shfl_xor(n, 8);
    if (n > 0.f) { cn += -p / n; cd += 1.f; }
  }
  if (lr != 0) { cn = 0.f; cd = 0.f; }
  cn += __shfl_xor(cn, 1); cn += __shfl_xor(cn, 2); cn += __shfl_xor(cn, 4);
  cn += __shfl_xor(cn, 8); cn += __shfl_xor(cn, 16); cn += __shfl_xor(cn, 32);
  cd += __shfl_xor(cd, 1); cd += __shfl_xor(cd, 2); cd += __shfl_xor(cd, 4);
  cd += __shfl_xor(cd, 8); cd += __shfl_xor(cd, 16); cd += __shfl_xor(cd, 32);
  if (lane == 0) { red[w][0] = cn; red[w][1] = cd; }
  __syncthreads();
  if (t == 0) {
    float num = red[0][0] + red[1][0] + red[2][0] + red[3][0];
    float den = red[0][1] + red[1][1] + red[2][1] + red[3][1];
    partials[(b * 32 + rb) * 2 + 0] = num;
    partials[(b * 32 + rb) * 2 + 1] = den;
  }
}

// ---------------------------------------------------------------- kernel 4
__global__ void pcl_final(const float* __restrict__ partials, float* __restrict__ out) {
  int t = threadIdx.x;
  float v = 0.f;
  if (t < NB) {
    float num = 0.f, den = 0.f;
    for (int r = 0; r < 32; ++r) {
      num += partials[(t * 32 + r) * 2 + 0];
      den += partials[(t * 32 + r) * 2 + 1];
    }
    v = num / fmaxf(den, 1.f);
  }
  v += __shfl_xor(v, 1);  v += __shfl_xor(v, 2);  v += __shfl_xor(v, 4);
  v += __shfl_xor(v, 8);  v += __shfl_xor(v, 16); v += __shfl_xor(v, 32);
  if (t == 0) out[0] = v / (float)NB;
}

}  // namespace

extern "C" void kernel_launch(void* const* d_in, const int* in_sizes, int n_in,
                              void* d_out, int out_size, void* d_ws, size_t ws_size,
                              hipStream_t stream) {
  (void)in_sizes; (void)n_in; (void)out_size; (void)ws_size;
  const float* feats  = (const float*)d_in[0];
  const int*   labels = (const int*)d_in[1];
  float* out = (float*)d_out;
  char* ws = (char*)d_ws;

  int* sel_lab = (int*)ws;                                   // 64 KB
  int* sel_idx = (int*)(ws + (64 << 10));                    // 64 KB
  __hip_bfloat16* SF = (__hip_bfloat16*)(ws + (128 << 10));  // 8 MB
  float* partials = (float*)(ws + (128 << 10) + (size_t)NB * NK * NC * 2);

  pcl_sample<<<NB, 256, 0, stream>>>(labels, sel_lab, sel_idx);
  pcl_gather<<<NB * NK, 256, 0, stream>>>(feats, sel_lab, sel_idx, SF);
  pcl_main<<<dim3(32, NB), 256, 0, stream>>>((const unsigned short*)SF, sel_lab, partials);
  pcl_final<<<1, 64, 0, stream>>>(partials, out);
}

// Round 2
// 136.991 us; speedup vs baseline: 1.8269x; 1.8269x over previous
//
#include <hip/hip_runtime.h>
#include <hip/hip_bf16.h>

namespace {

constexpr int NB  = 16;
constexpr int NC  = 256;
constexpr int NHW = 16384;
constexpr int NK  = 1024;
constexpr int IGN = 255;
constexpr float INVT = 14.285714285714285714f;  // 1/0.07

typedef __attribute__((ext_vector_type(8))) short short8;
typedef __attribute__((ext_vector_type(16))) float f32x16;
typedef unsigned int u32;

__device__ __forceinline__ void gl_lds16(const void* g, void* l) {
  __builtin_amdgcn_global_load_lds((const __attribute__((address_space(1))) u32*)g,
                                   (__attribute__((address_space(3))) u32*)l, 16, 0, 0);
}

// Stage a 64-row x 256-ch bf16 tile into LDS with chunk ^= (row&15) swizzle
// (pre-swizzled global source, linear LDS dest as global_load_lds requires).
__device__ __forceinline__ void stage64(const unsigned short* __restrict__ src,
                                        short* __restrict__ lds, int t) {
#pragma unroll
  for (int it = 0; it < 8; ++it) {
    int n = it * 256 + t;          // 16B slot id; wave-uniform base + lane*16
    int row = n >> 5, ch = n & 31;
    gl_lds16(src + row * NC + ((ch ^ (row & 15)) << 3), lds + (size_t)n * 8);
  }
}

// ---------------------------------------------------------------- kernel 1
__global__ __launch_bounds__(256) void pcl_sample(const int* __restrict__ labels,
                                                  int* __restrict__ sel_lab,
                                                  int* __restrict__ sel_idx) {
  const int b = blockIdx.x;
  const int t = threadIdx.x;
  const int* lab = labels + b * NHW;
  __shared__ int cfg_s[256], cbg_s[256];
  __shared__ int pfg_s[256], pbg_s[256];
  __shared__ int tot_fg;

  for (int k = t; k < NK; k += 256) {
    sel_lab[b * NK + k] = IGN;
    sel_idx[b * NK + k] = 0;
  }

  const int start = t * 64;
  int cfg = 0, cbg = 0;
  for (int i = 0; i < 64; ++i) {
    int L = lab[start + i];
    if (L == IGN) continue;
    if (L == 0) ++cbg; else ++cfg;
  }
  cfg_s[t] = cfg; cbg_s[t] = cbg;
  __syncthreads();
  if (t == 0) {
    int af = 0, ab = 0;
    for (int i = 0; i < 256; ++i) {
      pfg_s[i] = af; af += cfg_s[i];
      pbg_s[i] = ab; ab += cbg_s[i];
    }
    tot_fg = af;
  }
  __syncthreads();
  const int nfg = tot_fg;
  int rf  = pfg_s[t];
  int rbg = pbg_s[t];
  for (int i = 0; i < 64; ++i) {
    int p = start + i;
    int L = lab[p];
    if (L == IGN) continue;
    if (L == 0) {
      int slot = nfg + rbg;
      if (slot < NK) { sel_lab[b * NK + slot] = L; sel_idx[b * NK + slot] = p; }
      ++rbg;
    } else {
      if (rf < NK) { sel_lab[b * NK + rf] = L; sel_idx[b * NK + rf] = p; }
      ++rf;
    }
  }
}

// ---------------------------------------------------------------- kernel 2
// Coalesced gather + L2-normalize. Block = (image, 64 samples). Lane = sample,
// wave = channel quarter; LDS transpose for vectorized bf16 writeout.
__global__ __launch_bounds__(256) void pcl_gather(const float* __restrict__ feats,
                                                  const int* __restrict__ sel_lab,
                                                  const int* __restrict__ sel_idx,
                                                  unsigned short* __restrict__ SF) {
  const int b = blockIdx.x >> 4, kb = blockIdx.x & 15;
  const int t = threadIdx.x, lane = t & 63, w = t >> 6;
  __shared__ float fbuf[64][257];
  __shared__ float sqs[4][64];
  __shared__ float rn[64];
  const int gk = b * NK + kb * 64 + lane;
  const int lb = sel_lab[gk];
  const int p = (lb != IGN) ? sel_idx[gk] : -1;
  const float* fb = feats + (size_t)b * NC * NHW;
  float sq = 0.f;
#pragma unroll 4
  for (int cc = 0; cc < 64; ++cc) {
    int c = w * 64 + cc;
    float v = (p >= 0) ? fb[(size_t)c * NHW + p] : 0.f;
    fbuf[lane][c] = v;
    sq += v * v;
  }
  sqs[w][lane] = sq;
  __syncthreads();
  if (t < 64) {
    float s = sqs[0][t] + sqs[1][t] + sqs[2][t] + sqs[3][t];
    rn[t] = 1.f / fmaxf(sqrtf(s), 1e-12f);
  }
  __syncthreads();
#pragma unroll
  for (int it = 0; it < 8; ++it) {
    int slot = it * 256 + t;
    int s = slot >> 5, ch = slot & 31;
    float r = rn[s];
    short8 v8;
#pragma unroll
    for (int e = 0; e < 8; ++e) {
      float x = fbuf[s][ch * 8 + e] * r;
      __hip_bfloat16 h = __float2bfloat16(x);
      unsigned short u; __builtin_memcpy(&u, &h, 2);
      v8[e] = (short)u;
    }
    *(short8*)(SF + ((size_t)(b * NK + kb * 64 + s)) * NC + ch * 8) = v8;
  }
}

// ---------------------------------------------------------------- kernel 3
// Block: 64-row strip of image i vs all 1024 cols of image jimg.
// mode self (q even): jimg=i, accumulate SN + raw pos row-sums -> SNd, Rii.
// mode cross (q odd): jimg=next(i), raw pos row-sums -> Rin, col-sums -> Cp.
// 32x32x16 bf16 MFMA, double-buffered LDS via global_load_lds + counted vmcnt.
__global__ __launch_bounds__(256, 2) void pcl_tiles(
    const unsigned short* __restrict__ SF, const int* __restrict__ sel_lab,
    float2* __restrict__ SNd, float4* __restrict__ Rii, float4* __restrict__ Rin,
    float4* __restrict__ Cp) {
  const int id = blockIdx.x;
  const int i = id & 15;                 // image (XCD-pinned: id%8 == i%8)
  const int q = id >> 4;                 // 0..31
  const bool selfmode = (q & 1) == 0;
  const int strip = q >> 1;              // 0..15
  const int jimg = selfmode ? i : ((i + 1) & 15);

  const int t = threadIdx.x, lane = t & 63, w = t >> 6;
  const int rw = w & 1, cw = w >> 1;
  const int l31 = lane & 31, hi = lane >> 5, l15 = lane & 15;

  __shared__ short buf[2][64 * 256];     // 2 x 32KB
  __shared__ float4 colAcc[64];
  __shared__ float4 rred[64];

  const unsigned short* SFr = SF + (size_t)i * (NK * NC) + strip * 64 * NC;
  const unsigned short* SFc = SF + (size_t)jimg * (NK * NC);

  // prologue: rows -> buf0, col tile0 -> buf1
  stage64(SFr, buf[0], t);
  stage64(SFc, buf[1], t);
  __syncthreads();

  // A fragments (rows rw*32 + l31, all K=256) from buf0, then free buf0
  short8 afrag[16];
  {
    const char* ab = (const char*)buf[0] + (rw * 32 + l31) * 512;
#pragma unroll
    for (int s = 0; s < 16; ++s)
      afrag[s] = *(const short8*)(ab + (((2 * s + hi) ^ l15) << 4));
  }
  __syncthreads();
  stage64(SFc + 64 * NC, buf[0], t);     // col tile1 -> buf0

  int rlab[16];
#pragma unroll
  for (int j = 0; j < 16; ++j) {
    int rq = (j & 3) + 8 * (j >> 2) + 4 * hi;
    int L = sel_lab[i * NK + strip * 64 + rw * 32 + rq];
    rlab[j] = (L == IGN) ? -1 : L;
  }

  float S1[16], NP[16], PE[16], SNL[16];
#pragma unroll
  for (int j = 0; j < 16; ++j) { S1[j] = 0; NP[j] = 0; PE[j] = 0; SNL[j] = 0; }
  float cS1 = 0.f, cNP = 0.f, cPE = 0.f;

  int clab_cur = sel_lab[jimg * NK + cw * 32 + l31];

  for (int ct = 0; ct < 16; ++ct) {
    int clab_nxt = (ct < 15) ? sel_lab[jimg * NK + (ct + 1) * 64 + cw * 32 + l31] : 0;

    const char* bb = (const char*)buf[(ct & 1) ^ 1] + (cw * 32 + l31) * 512;
    f32x16 acc;
#pragma unroll
    for (int j = 0; j < 16; ++j) acc[j] = 0.f;
#pragma unroll
    for (int s = 0; s < 16; ++s) {
      short8 bfrag = *(const short8*)(bb + (((2 * s + hi) ^ l15) << 4));
      acc = __builtin_amdgcn_mfma_f32_32x32x16_bf16(afrag[s], bfrag, acc, 0, 0, 0);
    }

    const int gc = ct * 64 + cw * 32 + l31;
    const bool cvv = (clab_cur != IGN);
#pragma unroll
    for (int j = 0; j < 16; ++j) {
      float ls = acc[j] * INVT - INVT;     // logit - 1/T  (row max == 1/T)
      float E = __expf(ls);
      bool same = (rlab[j] == clab_cur);
      bool pmb = cvv && same;
      if (selfmode) {
        int rgj = strip * 64 + rw * 32 + (j & 3) + 8 * (j >> 2) + 4 * hi;
        pmb = pmb && (rgj != gc);
        SNL[j] += (cvv && !same) ? E : 0.f;
      }
      float pm = pmb ? 1.f : 0.f;
      S1[j] += pm * ls; NP[j] += pm; PE[j] += pm * E;
      if (!selfmode) { cS1 += pm * ls; cNP += pm; cPE += pm * E; }
    }

    if (!selfmode) {                       // col partial: combine hi halves + rw pair
      cS1 += __shfl_xor(cS1, 32);
      cNP += __shfl_xor(cNP, 32);
      cPE += __shfl_xor(cPE, 32);
      if (rw == 0 && hi == 0) colAcc[cw * 32 + l31] = make_float4(cS1, cNP, cPE, 0.f);
      asm volatile("s_waitcnt lgkmcnt(0)" ::: "memory");
    }
    asm volatile("" ::: "memory");
    __builtin_amdgcn_s_barrier();          // all waves done reading buf[cur]
    asm volatile("" ::: "memory");
    if (!selfmode && rw == 1 && hi == 0) {
      float4 o = colAcc[cw * 32 + l31];
      Cp[(i * 16 + strip) * NK + gc] = make_float4(cS1 + o.x, cNP + o.y, cPE + o.z, 0.f);
    }
    cS1 = 0.f; cNP = 0.f; cPE = 0.f;

    if (ct < 15) {
      if (ct < 14) {
        stage64(SFc + (ct + 2) * 64 * NC, buf[(ct & 1) ^ 1], t);
        asm volatile("s_waitcnt vmcnt(8)" ::: "memory");   // tile ct+1 landed
      } else {
        asm volatile("s_waitcnt vmcnt(0)" ::: "memory");
      }
      __builtin_amdgcn_s_barrier();
      asm volatile("" ::: "memory");
    }
    clab_cur = clab_nxt;
  }

  // row-sum reduce: over 32-lane half (this wave's cols), then across cw pair
#pragma unroll
  for (int j = 0; j < 16; ++j) {
    float s1 = S1[j], np = NP[j], pe = PE[j], sl = SNL[j];
#pragma unroll
    for (int m = 1; m <= 16; m <<= 1) {
      s1 += __shfl_xor(s1, m); np += __shfl_xor(np, m);
      pe += __shfl_xor(pe, m); sl += __shfl_xor(sl, m);
    }
    S1[j] = s1; NP[j] = np; PE[j] = pe; SNL[j] = sl;
  }
#pragma unroll
  for (int j = 0; j < 16; ++j) {
    int rq = (j & 3) + 8 * (j >> 2) + 4 * hi;
    if (cw == 0 && l31 == rq) rred[rw * 32 + rq] = make_float4(S1[j], NP[j], PE[j], SNL[j]);
  }
  __syncthreads();
#pragma unroll
  for (int j = 0; j < 16; ++j) {
    int rq = (j & 3) + 8 * (j >> 2) + 4 * hi;
    if (cw == 1 && l31 == rq) {
      float4 o = rred[rw * 32 + rq];
      int rgj = i * NK + strip * 64 + rw * 32 + rq;
      float4 tot = make_float4(S1[j] + o.x, NP[j] + o.y, PE[j] + o.z, SNL[j] + o.w);
      if (selfmode) {
        float sn = tot.w + 1e-8f;
        SNd[rgj] = make_float2(__logf(sn), 1.f / sn);
        Rii[rgj] = make_float4(tot.x, tot.y, tot.z, 0.f);
      } else {
        Rin[rgj] = make_float4(tot.x, tot.y, tot.z, 0.f);
      }
    }
  }
}

// ---------------------------------------------------------------- kernel 4
// Fold raw sums with LSN/rSN, assemble per-image anchor aggregates.
__global__ __launch_bounds__(256) void pcl_assemble(const float4* __restrict__ Rii,
                                                    const float4* __restrict__ Rin,
                                                    const float4* __restrict__ Cp,
                                                    const float2* __restrict__ SNd,
                                                    float* __restrict__ Aimg) {
  const int i = blockIdx.x, t = threadIdx.x;
  const int prev = (i + 15) & 15;
  float a1n = 0, a1c = 0, a2n = 0, a2c = 0;
  for (int r = t; r < NK; r += 256) {
    float4 rii = Rii[i * NK + r];
    float4 rin = Rin[i * NK + r];
    float2 sn = SNd[i * NK + r];
    float pp_ii = rii.x - rii.y * sn.x - sn.y * rii.z;
    float pp_in = rin.x - rin.y * sn.x - sn.y * rin.z;
    float np1 = rii.y + rin.y;
    if (np1 > 0.f) { a1n -= (pp_ii + pp_in) / np1; a1c += 1.f; }
    float cs1 = 0, cnp = 0, cpe = 0;
#pragma unroll
    for (int s = 0; s < 16; ++s) {
      float4 c = Cp[(prev * 16 + s) * NK + r];
      cs1 += c.x; cnp += c.y; cpe += c.z;
    }
    float ppc = cs1 - cnp * sn.x - sn.y * cpe;
    float np2 = rii.y + cnp;
    if (np2 > 0.f) { a2n -= (pp_ii + ppc) / np2; a2c += 1.f; }
  }
  __shared__ float red[256][4];
  red[t][0] = a1n; red[t][1] = a1c; red[t][2] = a2n; red[t][3] = a2c;
  __syncthreads();
  for (int off = 128; off > 0; off >>= 1) {
    if (t < off) {
      red[t][0] += red[t + off][0]; red[t][1] += red[t + off][1];
      red[t][2] += red[t + off][2]; red[t][3] += red[t + off][3];
    }
    __syncthreads();
  }
  if (t == 0) {
    Aimg[i * 4 + 0] = red[0][0]; Aimg[i * 4 + 1] = red[0][1];
    Aimg[i * 4 + 2] = red[0][2]; Aimg[i * 4 + 3] = red[0][3];
  }
}

// ---------------------------------------------------------------- kernel 5
__global__ void pcl_final(const float* __restrict__ Aimg, float* __restrict__ out) {
  int t = threadIdx.x;
  float v = 0.f;
  if (t < NB) {
    int nb = (t + 1) & 15;
    float num = Aimg[t * 4 + 0] + Aimg[nb * 4 + 2];
    float cnt = Aimg[t * 4 + 1] + Aimg[nb * 4 + 3];
    v = num / fmaxf(cnt, 1.f);
  }
  v += __shfl_xor(v, 1);  v += __shfl_xor(v, 2);  v += __shfl_xor(v, 4);
  v += __shfl_xor(v, 8);  v += __shfl_xor(v, 16); v += __shfl_xor(v, 32);
  if (t == 0) out[0] = v / (float)NB;
}

}  // namespace

extern "C" void kernel_launch(void* const* d_in, const int* in_sizes, int n_in,
                              void* d_out, int out_size, void* d_ws, size_t ws_size,
                              hipStream_t stream) {
  (void)in_sizes; (void)n_in; (void)out_size; (void)ws_size;
  const float* feats  = (const float*)d_in[0];
  const int*   labels = (const int*)d_in[1];
  float* out = (float*)d_out;
  char* ws = (char*)d_ws;

  int* sel_lab = (int*)ws;                                       // 64 KB
  int* sel_idx = (int*)(ws + (64 << 10));                        // 64 KB
  unsigned short* SF = (unsigned short*)(ws + (128 << 10));      // 8 MB
  size_t off = (128 << 10) + (size_t)NB * NK * NC * 2;
  float2* SNd = (float2*)(ws + off);  off += (size_t)NB * NK * 8;    // 128 KB
  float4* Rii = (float4*)(ws + off);  off += (size_t)NB * NK * 16;   // 256 KB
  float4* Rin = (float4*)(ws + off);  off += (size_t)NB * NK * 16;   // 256 KB
  float4* Cp  = (float4*)(ws + off);  off += (size_t)NB * 16 * NK * 16;  // 4 MB
  float* Aimg = (float*)(ws + off);

  pcl_sample<<<NB, 256, 0, stream>>>(labels, sel_lab, sel_idx);
  pcl_gather<<<256, 256, 0, stream>>>(feats, sel_lab, sel_idx, SF);
  pcl_tiles<<<512, 256, 0, stream>>>(SF, sel_lab, SNd, Rii, Rin, Cp);
  pcl_assemble<<<16, 256, 0, stream>>>(Rii, Rin, Cp, SNd, Aimg);
  pcl_final<<<1, 64, 0, stream>>>(Aimg, out);
}

// Round 3
// 115.439 us; speedup vs baseline: 2.1680x; 1.1867x over previous
//
#include <hip/hip_runtime.h>
#include <hip/hip_bf16.h>

namespace {

constexpr int NB  = 16;
constexpr int NC  = 256;
constexpr int NHW = 16384;
constexpr int NK  = 1024;
constexpr int IGN = 255;
constexpr float SCALE = 4.5398164f;   // sqrt((1/0.07) * log2(e))
constexpr float CBIAS = 20.609929f;   // (1/0.07) * log2(e)
constexpr float LN2   = 0.69314718f;

typedef __attribute__((ext_vector_type(8))) short short8;
typedef __attribute__((ext_vector_type(16))) float f32x16;
typedef unsigned int u32;

#define ASM_VMCNT8 asm volatile("s_waitcnt vmcnt(8)" ::: "memory")
#define ASM_VMCNT0 asm volatile("s_waitcnt vmcnt(0)" ::: "memory")
#define ASM_LGKM0  asm volatile("s_waitcnt lgkmcnt(0)" ::: "memory")
#define SCHEDB     __builtin_amdgcn_sched_barrier(0)
#define MEMFENCE   asm volatile("" ::: "memory")
#define BARRIER    __builtin_amdgcn_s_barrier()

__device__ __forceinline__ float fexp2(float x) {
#if __has_builtin(__builtin_amdgcn_exp2f)
  return __builtin_amdgcn_exp2f(x);
#else
  return exp2f(x);
#endif
}

__device__ __forceinline__ void gl_lds16(const void* g, void* l) {
  __builtin_amdgcn_global_load_lds((const __attribute__((address_space(1))) u32*)g,
                                   (__attribute__((address_space(3))) u32*)l, 16, 0, 0);
}

// ---------------------------------------------------------------- kernel 1
// Stable-priority sampler. Coalesced LDS staging + wave-parallel scan.
__global__ __launch_bounds__(256) void pcl_sample(const int* __restrict__ labels,
                                                  int* __restrict__ sel_lab,
                                                  int* __restrict__ sel_idx,
                                                  int* __restrict__ counter) {
  const int b = blockIdx.x, t = threadIdx.x, lane = t & 63, w = t >> 6;
  if (b == 0 && t == 0) counter[0] = 0;
  __shared__ int labL[NHW];      // 64 KB
  __shared__ int wtot[4];

  for (int k = t; k < NK; k += 256) {
    sel_lab[b * NK + k] = IGN;
    sel_idx[b * NK + k] = 0;
  }

  const int* lab = labels + b * NHW;
  // coalesced stage; position swizzled so chunk-scan readback is conflict-free
  for (int k = 0; k < 64; ++k) {
    int idx = k * 256 + t;
    int pos = (idx & ~63) | ((idx & 63) ^ ((idx >> 6) & 31));
    labL[pos] = lab[idx];
  }
  __syncthreads();

  const int base = t * 64, m5 = t & 31;
  int cfg = 0, cbg = 0;
  for (int i = 0; i < 64; ++i) {
    int L = labL[base + (i ^ m5)];
    cfg += (L != IGN && L != 0);
    cbg += (L == 0);
  }
  int packed = cfg | (cbg << 15);
  int incl = packed;
#pragma unroll
  for (int off = 1; off < 64; off <<= 1) {
    int n = __shfl_up(incl, off);
    if (lane >= off) incl += n;
  }
  if (lane == 63) wtot[w] = incl;
  __syncthreads();
  int wb = 0, total = 0;
  for (int ww = 0; ww < 4; ++ww) { int v = wtot[ww]; total += v; if (ww < w) wb += v; }
  int excl = incl - packed + wb;
  int rf  = excl & 32767;
  int rbg = (excl >> 15) & 32767;
  const int nfg = total & 32767;
  if (rf < NK || nfg + rbg < NK) {
    for (int i = 0; i < 64; ++i) {
      int L = labL[base + (i ^ m5)];
      if (L == IGN) continue;
      if (L != 0) {
        if (rf < NK) { sel_lab[b * NK + rf] = L; sel_idx[b * NK + rf] = base + i; }
        ++rf;
      } else {
        int s = nfg + rbg;
        if (s < NK) { sel_lab[b * NK + s] = L; sel_idx[b * NK + s] = base + i; }
        ++rbg;
      }
    }
  }
}

// ---------------------------------------------------------------- kernel 2
// Gather + L2-normalize + pre-scale by SCALE, store bf16. 16 waves/block.
__global__ __launch_bounds__(1024) void pcl_gather(const float* __restrict__ feats,
                                                   const int* __restrict__ sel_lab,
                                                   const int* __restrict__ sel_idx,
                                                   unsigned short* __restrict__ SF) {
  const int b = blockIdx.x >> 4, kb = blockIdx.x & 15;
  const int t = threadIdx.x, s = t & 63, w = t >> 6;   // sample s, channel group w
  __shared__ float fbuf[64][257];
  __shared__ float sqs[16][64];
  __shared__ float rn[64];
  const int gk = b * NK + kb * 64 + s;
  const int lb = sel_lab[gk];
  const int p = (lb != IGN) ? sel_idx[gk] : -1;
  const float* fb = feats + (size_t)b * NC * NHW;
  float sq = 0.f;
#pragma unroll
  for (int cc = 0; cc < 16; ++cc) {
    int c = w * 16 + cc;
    float v = (p >= 0) ? fb[(size_t)c * NHW + p] : 0.f;
    fbuf[s][c] = v;
    sq += v * v;
  }
  sqs[w][s] = sq;
  __syncthreads();
  if (t < 64) {
    float tot = 0.f;
#pragma unroll
    for (int k2 = 0; k2 < 16; ++k2) tot += sqs[k2][t];
    rn[t] = SCALE / fmaxf(sqrtf(tot), 1e-12f);
  }
  __syncthreads();
#pragma unroll
  for (int it = 0; it < 2; ++it) {
    int slot = it * 1024 + t;
    int ss = slot >> 5, ch = slot & 31;
    float r = rn[ss];
    short8 v8;
#pragma unroll
    for (int e = 0; e < 8; ++e) {
      float x = fbuf[ss][ch * 8 + e] * r;
      __hip_bfloat16 h = __float2bfloat16(x);
      unsigned short u; __builtin_memcpy(&u, &h, 2);
      v8[e] = (short)u;
    }
    *(short8*)(SF + ((size_t)(b * NK + kb * 64 + ss)) * NC + ch * 8) = v8;
  }
}

// ---------------------------------------------------------------- kernel 3
// Block (i, strip): 64 rows of image i vs 2048 cols (self 1024 + next 1024).
// 8 waves, 128-col rounds, 32x32x16 bf16 MFMA, gl_lds double-buffer + counted
// vmcnt. Outputs: SNd, Rii (self), Rin (cross rows), Cp (cross col sums).
__global__ __launch_bounds__(512, 2) void pcl_tiles(
    const unsigned short* __restrict__ SF, const int* __restrict__ sel_lab,
    float2* __restrict__ SNd, float4* __restrict__ Rii, float4* __restrict__ Rin,
    float4* __restrict__ Cp) {
  const int id = blockIdx.x;
  const int i = id & 15, strip = id >> 4, inxt = (i + 1) & 15;
  const int t = threadIdx.x, lane = t & 63, w = t >> 6;
  const int rw = w & 1, cw = w >> 1;          // row half, col quarter
  const int l31 = lane & 31, hi = lane >> 5, l15 = lane & 15;

  __shared__ short buf[2][128 * 256];          // 2 x 64 KB
  __shared__ float4 colAcc[128];
  __shared__ float4 rred[4][64];

  const unsigned short* SFrow = SF + (size_t)i * (NK * NC) + strip * 64 * NC;

  auto stage_round = [&](int rr) {
    const unsigned short* base =
        SF + (size_t)((rr < 8) ? i : inxt) * (NK * NC) + ((rr & 7) * 128) * NC;
    short* dst = buf[rr & 1];
#pragma unroll
    for (int it = 0; it < 8; ++it) {
      int n = it * 512 + t, row = n >> 5, ch = n & 31;
      gl_lds16(base + row * NC + ((ch ^ (row & 15)) << 3), dst + (size_t)n * 8);
    }
  };

  // ---- prologue: rows -> buf0, extract A fragments, then reuse buf0 ----
#pragma unroll
  for (int it = 0; it < 4; ++it) {
    int n = it * 512 + t, row = n >> 5, ch = n & 31;
    gl_lds16(SFrow + row * NC + ((ch ^ (row & 15)) << 3), buf[0] + (size_t)n * 8);
  }
  ASM_VMCNT0; MEMFENCE; BARRIER; MEMFENCE;

  short8 afrag[16];
  {
    const char* ab = (const char*)buf[0] + (rw * 32 + l31) * 512;
#pragma unroll
    for (int s2 = 0; s2 < 16; ++s2)
      afrag[s2] = *(const short8*)(ab + (((2 * s2 + hi) ^ l15) << 4));
  }
  ASM_LGKM0; SCHEDB; MEMFENCE; BARRIER; MEMFENCE;   // buf0 free

  stage_round(0);
  stage_round(1);

  int rlab[16];
#pragma unroll
  for (int j = 0; j < 16; ++j) {
    int rq = (j & 3) + 8 * (j >> 2) + 4 * hi;
    int L = sel_lab[i * NK + strip * 64 + rw * 32 + rq];
    rlab[j] = (L == IGN) ? -1 : L;
  }
  const int cb = cw * 32 + l31;                // col within 128-round
  int cl; float cvf;
  { int L = sel_lab[i * NK + cb]; cl = (L == IGN) ? -2 : L; cvf = (L == IGN) ? 0.f : 1.f; }

  ASM_VMCNT8; MEMFENCE; BARRIER; MEMFENCE;     // round 0 ready

  float S1[16], NP[16], PE[16], SNL[16];
#pragma unroll
  for (int j = 0; j < 16; ++j) { S1[j] = 0.f; NP[j] = 0.f; PE[j] = 0.f; SNL[j] = 0.f; }

  // ================= SELF rounds 0..7 =================
  for (int r = 0; r < 8; ++r) {
    int Ln;
    { int jn = (r + 1 < 8) ? i : inxt; Ln = sel_lab[jn * NK + ((r + 1) & 7) * 128 + cb]; }

    const char* bb = (const char*)buf[r & 1] + cb * 512;
    f32x16 acc;
#pragma unroll
    for (int j = 0; j < 16; ++j) acc[j] = 0.f;
    __builtin_amdgcn_s_setprio(1);
#pragma unroll
    for (int s2 = 0; s2 < 16; ++s2) {
      short8 bfr = *(const short8*)(bb + (((2 * s2 + hi) ^ l15) << 4));
      acc = __builtin_amdgcn_mfma_f32_32x32x16_bf16(afrag[s2], bfr, acc, 0, 0, 0);
    }
    __builtin_amdgcn_s_setprio(0);

    const int sc2 = r * 128 + cb - strip * 64 - rw * 32 - 4 * hi;  // self-col marker
#pragma unroll
    for (int j = 0; j < 16; ++j) {
      float y = acc[j] - CBIAS;
      float E = fexp2(y);
      float pm = (rlab[j] == cl) ? 1.f : 0.f;
      float nm = cvf - pm;
      if (((j & 3) + 8 * (j >> 2)) == sc2) pm = 0.f;   // exclude self pair
      S1[j] += pm * y; NP[j] += pm; PE[j] += pm * E; SNL[j] += nm * E;
    }

    MEMFENCE; BARRIER; MEMFENCE;               // all waves done reading buf[r&1]
    stage_round(r + 2);
    ASM_VMCNT8;
    MEMFENCE; BARRIER; MEMFENCE;               // round r+1 ready
    cl = (Ln == IGN) ? -2 : Ln; cvf = (Ln == IGN) ? 0.f : 1.f;
  }

  // ---- fold self stats -> SNd, Rii; reset for cross ----
#pragma unroll
  for (int j = 0; j < 16; ++j) {
    float a = S1[j], b2 = NP[j], c = PE[j], d = SNL[j];
#pragma unroll
    for (int m = 1; m <= 16; m <<= 1) {
      a += __shfl_xor(a, m); b2 += __shfl_xor(b2, m);
      c += __shfl_xor(c, m); d += __shfl_xor(d, m);
    }
    S1[j] = a; NP[j] = b2; PE[j] = c; SNL[j] = d;
  }
#pragma unroll
  for (int j = 0; j < 16; ++j) {
    int rq = (j & 3) + 8 * (j >> 2) + 4 * hi;
    if (l31 == rq) rred[cw][rw * 32 + rq] = make_float4(S1[j], NP[j], PE[j], SNL[j]);
  }
  __syncthreads();
  if (cw == 0) {
#pragma unroll
    for (int j = 0; j < 16; ++j) {
      int rq = (j & 3) + 8 * (j >> 2) + 4 * hi;
      if (l31 == rq) {
        int row = rw * 32 + rq;
        float4 A = rred[0][row], B = rred[1][row], C2 = rred[2][row], D = rred[3][row];
        float sn = A.w + B.w + C2.w + D.w + 1e-8f;
        int g = i * NK + strip * 64 + row;
        SNd[g] = make_float2(__logf(sn), 1.f / sn);
        Rii[g] = make_float4(A.x + B.x + C2.x + D.x, A.y + B.y + C2.y + D.y,
                             A.z + B.z + C2.z + D.z, 0.f);
      }
    }
  }
#pragma unroll
  for (int j = 0; j < 16; ++j) { S1[j] = 0.f; NP[j] = 0.f; PE[j] = 0.f; }
  __syncthreads();

  // ================= CROSS rounds 8..15 =================
  for (int r = 8; r < 16; ++r) {
    int Ln = 0;
    if (r < 15) Ln = sel_lab[inxt * NK + ((r + 1) & 7) * 128 + cb];

    const char* bb = (const char*)buf[r & 1] + cb * 512;
    f32x16 acc;
#pragma unroll
    for (int j = 0; j < 16; ++j) acc[j] = 0.f;
    __builtin_amdgcn_s_setprio(1);
#pragma unroll
    for (int s2 = 0; s2 < 16; ++s2) {
      short8 bfr = *(const short8*)(bb + (((2 * s2 + hi) ^ l15) << 4));
      acc = __builtin_amdgcn_mfma_f32_32x32x16_bf16(afrag[s2], bfr, acc, 0, 0, 0);
    }
    __builtin_amdgcn_s_setprio(0);

    float cS1 = 0.f, cNP = 0.f, cPE = 0.f;
#pragma unroll
    for (int j = 0; j < 16; ++j) {
      float y = acc[j] - CBIAS;
      float E = fexp2(y);
      float pm = (rlab[j] == cl) ? 1.f : 0.f;
      S1[j] += pm * y; NP[j] += pm; PE[j] += pm * E;
      cS1 += pm * y; cNP += pm; cPE += pm * E;
    }
    cS1 += __shfl_xor(cS1, 32); cNP += __shfl_xor(cNP, 32); cPE += __shfl_xor(cPE, 32);
    if (rw == 0 && hi == 0) colAcc[cb] = make_float4(cS1, cNP, cPE, 0.f);
    ASM_LGKM0; SCHEDB;
    MEMFENCE; BARRIER; MEMFENCE;               // done reading buf[r&1]; colAcc visible
    if (rw == 1 && hi == 0) {
      float4 o = colAcc[cb];
      Cp[(i * 16 + strip) * NK + (r & 7) * 128 + cb] =
          make_float4(cS1 + o.x, cNP + o.y, cPE + o.z, 0.f);
    }
    if (r < 14) { stage_round(r + 2); ASM_VMCNT8; }
    else if (r == 14) { ASM_VMCNT0; }
    if (r < 15) { MEMFENCE; BARRIER; MEMFENCE; }
    cl = (Ln == IGN) ? -2 : Ln;
  }

  // ---- fold cross stats -> Rin ----
#pragma unroll
  for (int j = 0; j < 16; ++j) {
    float a = S1[j], b2 = NP[j], c = PE[j];
#pragma unroll
    for (int m = 1; m <= 16; m <<= 1) {
      a += __shfl_xor(a, m); b2 += __shfl_xor(b2, m); c += __shfl_xor(c, m);
    }
    S1[j] = a; NP[j] = b2; PE[j] = c;
  }
#pragma unroll
  for (int j = 0; j < 16; ++j) {
    int rq = (j & 3) + 8 * (j >> 2) + 4 * hi;
    if (l31 == rq) rred[cw][rw * 32 + rq] = make_float4(S1[j], NP[j], PE[j], 0.f);
  }
  __syncthreads();
  if (cw == 0) {
#pragma unroll
    for (int j = 0; j < 16; ++j) {
      int rq = (j & 3) + 8 * (j >> 2) + 4 * hi;
      if (l31 == rq) {
        int row = rw * 32 + rq;
        float4 A = rred[0][row], B = rred[1][row], C2 = rred[2][row], D = rred[3][row];
        Rin[i * NK + strip * 64 + row] =
            make_float4(A.x + B.x + C2.x + D.x, A.y + B.y + C2.y + D.y,
                        A.z + B.z + C2.z + D.z, 0.f);
      }
    }
  }
}

// ---------------------------------------------------------------- kernel 4
// Fold per-row raw sums + per-image aggregate; last block computes the loss.
__global__ __launch_bounds__(256) void pcl_assemble(const float4* __restrict__ Rii,
                                                    const float4* __restrict__ Rin,
                                                    const float4* __restrict__ Cp,
                                                    const float2* __restrict__ SNd,
                                                    float* __restrict__ Aimg,
                                                    int* __restrict__ counter,
                                                    float* __restrict__ out) {
  const int i = blockIdx.x, t = threadIdx.x, lane = t & 63, w = t >> 6;
  const int prev = (i + 15) & 15;
  float a1n = 0, a1c = 0, a2n = 0, a2c = 0;
  for (int r = t; r < NK; r += 256) {
    float4 rii = Rii[i * NK + r];
    float4 rin = Rin[i * NK + r];
    float2 sn = SNd[i * NK + r];
    float pp_ii = LN2 * rii.x - rii.y * sn.x - sn.y * rii.z;
    float pp_in = LN2 * rin.x - rin.y * sn.x - sn.y * rin.z;
    float np1 = rii.y + rin.y;
    if (np1 > 0.f) { a1n -= (pp_ii + pp_in) / np1; a1c += 1.f; }
    float cs1 = 0, cnp = 0, cpe = 0;
#pragma unroll
    for (int s2 = 0; s2 < 16; ++s2) {
      float4 c = Cp[(prev * 16 + s2) * NK + r];
      cs1 += c.x; cnp += c.y; cpe += c.z;
    }
    float ppc = LN2 * cs1 - cnp * sn.x - sn.y * cpe;
    float np2 = rii.y + cnp;
    if (np2 > 0.f) { a2n -= (pp_ii + ppc) / np2; a2c += 1.f; }
  }
#pragma unroll
  for (int m = 1; m <= 32; m <<= 1) {
    a1n += __shfl_xor(a1n, m); a1c += __shfl_xor(a1c, m);
    a2n += __shfl_xor(a2n, m); a2c += __shfl_xor(a2c, m);
  }
  __shared__ float wred[4][4];
  __shared__ int lastf;
  if (lane == 0) { wred[w][0] = a1n; wred[w][1] = a1c; wred[w][2] = a2n; wred[w][3] = a2c; }
  __syncthreads();
  if (t == 0) {
    Aimg[i * 4 + 0] = wred[0][0] + wred[1][0] + wred[2][0] + wred[3][0];
    Aimg[i * 4 + 1] = wred[0][1] + wred[1][1] + wred[2][1] + wred[3][1];
    Aimg[i * 4 + 2] = wred[0][2] + wred[1][2] + wred[2][2] + wred[3][2];
    Aimg[i * 4 + 3] = wred[0][3] + wred[1][3] + wred[2][3] + wred[3][3];
    __threadfence();
    int old = atomicAdd(counter, 1);
    lastf = (old == NB - 1);
  }
  __syncthreads();
  if (lastf && t < 64) {
    float v = 0.f;
    if (t < NB) {
      int nb = (t + 1) & 15;
      float num = __hip_atomic_load(&Aimg[t * 4 + 0], __ATOMIC_ACQUIRE, __HIP_MEMORY_SCOPE_AGENT)
                + __hip_atomic_load(&Aimg[nb * 4 + 2], __ATOMIC_ACQUIRE, __HIP_MEMORY_SCOPE_AGENT);
      float cnt = __hip_atomic_load(&Aimg[t * 4 + 1], __ATOMIC_ACQUIRE, __HIP_MEMORY_SCOPE_AGENT)
                + __hip_atomic_load(&Aimg[nb * 4 + 3], __ATOMIC_ACQUIRE, __HIP_MEMORY_SCOPE_AGENT);
      v = num / fmaxf(cnt, 1.f);
    }
    v += __shfl_xor(v, 1); v += __shfl_xor(v, 2); v += __shfl_xor(v, 4); v += __shfl_xor(v, 8);
    if (t == 0) out[0] = v / (float)NB;
  }
}

}  // namespace

extern "C" void kernel_launch(void* const* d_in, const int* in_sizes, int n_in,
                              void* d_out, int out_size, void* d_ws, size_t ws_size,
                              hipStream_t stream) {
  (void)in_sizes; (void)n_in; (void)out_size; (void)ws_size;
  const float* feats  = (const float*)d_in[0];
  const int*   labels = (const int*)d_in[1];
  float* out = (float*)d_out;
  char* ws = (char*)d_ws;

  int* sel_lab = (int*)ws;                                       // 64 KB
  int* sel_idx = (int*)(ws + (64 << 10));                        // 64 KB
  unsigned short* SF = (unsigned short*)(ws + (128 << 10));      // 8 MB
  size_t off = (128 << 10) + (size_t)NB * NK * NC * 2;
  float2* SNd = (float2*)(ws + off);  off += (size_t)NB * NK * 8;
  float4* Rii = (float4*)(ws + off);  off += (size_t)NB * NK * 16;
  float4* Rin = (float4*)(ws + off);  off += (size_t)NB * NK * 16;
  float4* Cp  = (float4*)(ws + off);  off += (size_t)NB * 16 * NK * 16;
  float* Aimg = (float*)(ws + off);   off += 64 * sizeof(float);
  int* counter = (int*)(ws + off);

  pcl_sample<<<NB, 256, 0, stream>>>(labels, sel_lab, sel_idx, counter);
  pcl_gather<<<256, 1024, 0, stream>>>(feats, sel_lab, sel_idx, SF);
  pcl_tiles<<<256, 512, 0, stream>>>(SF, sel_lab, SNd, Rii, Rin, Cp);
  pcl_assemble<<<NB, 256, 0, stream>>>(Rii, Rin, Cp, SNd, Aimg, counter, out);
}

// Round 4
// 92.400 us; speedup vs baseline: 2.7086x; 1.2493x over previous
//
#include <hip/hip_runtime.h>
#include <hip/hip_bf16.h>

namespace {

constexpr int NB  = 16;
constexpr int NC  = 256;
constexpr int NHW = 16384;
constexpr int NK  = 1024;
constexpr int IGN = 255;
constexpr float SCALE = 4.5398164f;   // sqrt((1/0.07) * log2(e))
constexpr float CBIAS = 20.609929f;   // (1/0.07) * log2(e)
constexpr float LN2   = 0.69314718f;

typedef __attribute__((ext_vector_type(8))) short short8;
typedef __attribute__((ext_vector_type(4))) float f32x4;
typedef unsigned int u32;

#define ASM_VMCNT8 asm volatile("s_waitcnt vmcnt(8)" ::: "memory")
#define ASM_VMCNT0 asm volatile("s_waitcnt vmcnt(0)" ::: "memory")
#define ASM_LGKM0  asm volatile("s_waitcnt lgkmcnt(0)" ::: "memory")
#define SCHEDB     __builtin_amdgcn_sched_barrier(0)
#define MEMFENCE   asm volatile("" ::: "memory")
#define BARRIER    __builtin_amdgcn_s_barrier()

__device__ __forceinline__ float fexp2(float x) {
#if __has_builtin(__builtin_amdgcn_exp2f)
  return __builtin_amdgcn_exp2f(x);
#else
  return exp2f(x);
#endif
}

__device__ __forceinline__ void gl_lds16(const void* g, void* l) {
  __builtin_amdgcn_global_load_lds((const __attribute__((address_space(1))) u32*)g,
                                   (__attribute__((address_space(3))) u32*)l, 16, 0, 0);
}

// ---------------------------------------------------------------- kernel 1
// Stable-priority sampler. Coalesced LDS staging + wave-parallel scan.
__global__ __launch_bounds__(256) void pcl_sample(const int* __restrict__ labels,
                                                  int* __restrict__ sel_lab,
                                                  int* __restrict__ sel_idx,
                                                  int* __restrict__ counter) {
  const int b = blockIdx.x, t = threadIdx.x, lane = t & 63, w = t >> 6;
  if (b == 0 && t == 0) counter[0] = 0;
  __shared__ int labL[NHW];      // 64 KB
  __shared__ int wtot[4];

  for (int k = t; k < NK; k += 256) {
    sel_lab[b * NK + k] = IGN;
    sel_idx[b * NK + k] = 0;
  }

  const int* lab = labels + b * NHW;
  for (int k = 0; k < 64; ++k) {
    int idx = k * 256 + t;
    int pos = (idx & ~63) | ((idx & 63) ^ ((idx >> 6) & 31));
    labL[pos] = lab[idx];
  }
  __syncthreads();

  const int base = t * 64, m5 = t & 31;
  int cfg = 0, cbg = 0;
  for (int i = 0; i < 64; ++i) {
    int L = labL[base + (i ^ m5)];
    cfg += (L != IGN && L != 0);
    cbg += (L == 0);
  }
  int packed = cfg | (cbg << 15);
  int incl = packed;
#pragma unroll
  for (int off = 1; off < 64; off <<= 1) {
    int n = __shfl_up(incl, off);
    if (lane >= off) incl += n;
  }
  if (lane == 63) wtot[w] = incl;
  __syncthreads();
  int wb = 0, total = 0;
  for (int ww = 0; ww < 4; ++ww) { int v = wtot[ww]; total += v; if (ww < w) wb += v; }
  int excl = incl - packed + wb;
  int rf  = excl & 32767;
  int rbg = (excl >> 15) & 32767;
  const int nfg = total & 32767;
  if (rf < NK || nfg + rbg < NK) {
    for (int i = 0; i < 64; ++i) {
      int L = labL[base + (i ^ m5)];
      if (L == IGN) continue;
      if (L != 0) {
        if (rf < NK) { sel_lab[b * NK + rf] = L; sel_idx[b * NK + rf] = base + i; }
        ++rf;
      } else {
        int s = nfg + rbg;
        if (s < NK) { sel_lab[b * NK + s] = L; sel_idx[b * NK + s] = base + i; }
        ++rbg;
      }
    }
  }
}

// ---------------------------------------------------------------- kernel 2
// Gather + L2-normalize + pre-scale by SCALE, store bf16. 16 waves/block.
__global__ __launch_bounds__(1024) void pcl_gather(const float* __restrict__ feats,
                                                   const int* __restrict__ sel_lab,
                                                   const int* __restrict__ sel_idx,
                                                   unsigned short* __restrict__ SF) {
  const int b = blockIdx.x >> 4, kb = blockIdx.x & 15;
  const int t = threadIdx.x, s = t & 63, w = t >> 6;   // sample s, channel group w
  __shared__ float fbuf[64][257];
  __shared__ float sqs[16][64];
  __shared__ float rn[64];
  const int gk = b * NK + kb * 64 + s;
  const int lb = sel_lab[gk];
  const int p = (lb != IGN) ? sel_idx[gk] : -1;
  const float* fb = feats + (size_t)b * NC * NHW;
  float sq = 0.f;
#pragma unroll
  for (int cc = 0; cc < 16; ++cc) {
    int c = w * 16 + cc;
    float v = (p >= 0) ? fb[(size_t)c * NHW + p] : 0.f;
    fbuf[s][c] = v;
    sq += v * v;
  }
  sqs[w][s] = sq;
  __syncthreads();
  if (t < 64) {
    float tot = 0.f;
#pragma unroll
    for (int k2 = 0; k2 < 16; ++k2) tot += sqs[k2][t];
    rn[t] = SCALE / fmaxf(sqrtf(tot), 1e-12f);
  }
  __syncthreads();
#pragma unroll
  for (int it = 0; it < 2; ++it) {
    int slot = it * 1024 + t;
    int ss = slot >> 5, ch = slot & 31;
    float r = rn[ss];
    short8 v8;
#pragma unroll
    for (int e = 0; e < 8; ++e) {
      float x = fbuf[ss][ch * 8 + e] * r;
      __hip_bfloat16 h = __float2bfloat16(x);
      unsigned short u; __builtin_memcpy(&u, &h, 2);
      v8[e] = (short)u;
    }
    *(short8*)(SF + ((size_t)(b * NK + kb * 64 + ss)) * NC + ch * 8) = v8;
  }
}

// ---------------------------------------------------------------- kernel 3
// Block (i, strip): 64 rows of image i vs 2048 cols (self 1024 + next 1024).
// 8 waves = (row-tile rw 0..3 of 16 rows) x (col-half ch2 0..1 of 64 cols).
// 16x16x32 bf16 MFMA (low VGPR, spill-proof), 128-col rounds, gl_lds
// double-buffer + counted vmcnt. Outputs: SNd, Rii, Rin, Cp.
__global__ __launch_bounds__(512) void pcl_tiles(
    const unsigned short* __restrict__ SF, const int* __restrict__ sel_lab,
    float2* __restrict__ SNd, float4* __restrict__ Rii, float4* __restrict__ Rin,
    float4* __restrict__ Cp) {
  const int id = blockIdx.x;
  const int i = id & 15, strip = id >> 4, inxt = (i + 1) & 15;
  const int t = threadIdx.x, lane = t & 63, w = t >> 6;
  const int rw = w & 3, ch2 = w >> 2;
  const int lg = lane >> 4, lr = lane & 15;

  __shared__ short buf[2][128 * 256];          // 2 x 64 KB
  __shared__ float4 colAcc[4][128];            // 8 KB
  __shared__ float4 rred[2][64];               // 2 KB

  const unsigned short* SFrow = SF + (size_t)i * (NK * NC) + strip * 64 * NC;

  auto stage_round = [&](int rr) {
    const unsigned short* base =
        SF + (size_t)((rr < 8) ? i : inxt) * (NK * NC) + ((rr & 7) * 128) * NC;
    short* dst = buf[rr & 1];
#pragma unroll
    for (int it = 0; it < 8; ++it) {
      int n = it * 512 + t, row = n >> 5, ch = n & 31;
      gl_lds16(base + row * NC + ((ch ^ (row & 15)) << 3), dst + (size_t)n * 8);
    }
  };

  // ---- prologue: 64 rows -> buf0 (32KB), extract A fragments, reuse buf0 ----
#pragma unroll
  for (int it = 0; it < 4; ++it) {
    int n = it * 512 + t, row = n >> 5, ch = n & 31;
    gl_lds16(SFrow + row * NC + ((ch ^ (row & 15)) << 3), buf[0] + (size_t)n * 8);
  }
  ASM_VMCNT0; MEMFENCE; BARRIER; MEMFENCE;

  short8 afrag[8];
  const int arow = rw * 16 + lr;
#pragma unroll
  for (int ks = 0; ks < 8; ++ks) {
    int ch = ks * 4 + lg;
    afrag[ks] = *(const short8*)(buf[0] + arow * 256 + ((ch ^ (arow & 15)) << 3));
  }
  ASM_LGKM0; SCHEDB; MEMFENCE; BARRIER; MEMFENCE;   // buf0 free

  stage_round(0);
  stage_round(1);

  int rlab[4];
#pragma unroll
  for (int jj = 0; jj < 4; ++jj) {
    int L = sel_lab[i * NK + strip * 64 + rw * 16 + 4 * lg + jj];
    rlab[jj] = (L == IGN) ? -1 : L;
  }

  ASM_VMCNT8; MEMFENCE; BARRIER; MEMFENCE;     // round 0 ready

  float S1[4], NP[4], PE[4], SNL[4];
#pragma unroll
  for (int jj = 0; jj < 4; ++jj) { S1[jj] = 0.f; NP[jj] = 0.f; PE[jj] = 0.f; SNL[jj] = 0.f; }

  // ================= SELF rounds 0..7 =================
  for (int r = 0; r < 8; ++r) {
    int cl[4];
#pragma unroll
    for (int c2 = 0; c2 < 4; ++c2)
      cl[c2] = sel_lab[i * NK + r * 128 + ch2 * 64 + c2 * 16 + lr];

    const short* bbase = buf[r & 1];
    f32x4 acc[4];
#pragma unroll
    for (int c2 = 0; c2 < 4; ++c2) acc[c2] = f32x4{0.f, 0.f, 0.f, 0.f};
#pragma unroll
    for (int ks = 0; ks < 8; ++ks) {
      int ch = ks * 4 + lg;
      short8 af = afrag[ks];
#pragma unroll
      for (int c2 = 0; c2 < 4; ++c2) {
        int brow = ch2 * 64 + c2 * 16 + lr;
        short8 bf = *(const short8*)(bbase + brow * 256 + ((ch ^ (brow & 15)) << 3));
        acc[c2] = __builtin_amdgcn_mfma_f32_16x16x32_bf16(af, bf, acc[c2], 0, 0, 0);
      }
    }

    const int grb = strip * 64 + rw * 16 + 4 * lg;
#pragma unroll
    for (int c2 = 0; c2 < 4; ++c2) {
      const bool cv = (cl[c2] != IGN);
      const int gc = r * 128 + ch2 * 64 + c2 * 16 + lr;
#pragma unroll
      for (int jj = 0; jj < 4; ++jj) {
        float y = acc[c2][jj] - CBIAS;
        float E = fexp2(y);
        bool pos = cv && (rlab[jj] == cl[c2]) && (grb + jj != gc);
        bool neg = cv && (rlab[jj] != cl[c2]);
        float pm = pos ? 1.f : 0.f;
        S1[jj] += pm * y; NP[jj] += pm; PE[jj] += pm * E;
        SNL[jj] += neg ? E : 0.f;
      }
    }

    MEMFENCE; BARRIER; MEMFENCE;               // all waves done reading buf[r&1]
    stage_round(r + 2);
    ASM_VMCNT8;
    MEMFENCE; BARRIER; MEMFENCE;               // round r+1 ready
  }

  // ---- fold self stats -> SNd, Rii ----
#pragma unroll
  for (int jj = 0; jj < 4; ++jj) {
    float a = S1[jj], b4 = NP[jj], c4 = PE[jj], d4 = SNL[jj];
#pragma unroll
    for (int m = 1; m <= 8; m <<= 1) {
      a += __shfl_xor(a, m); b4 += __shfl_xor(b4, m);
      c4 += __shfl_xor(c4, m); d4 += __shfl_xor(d4, m);
    }
    if (lr == 4 * lg + jj) rred[ch2][rw * 16 + 4 * lg + jj] = make_float4(a, b4, c4, d4);
  }
  ASM_LGKM0; SCHEDB; MEMFENCE; BARRIER; MEMFENCE;
  if (ch2 == 0) {
#pragma unroll
    for (int jj = 0; jj < 4; ++jj) {
      if (lr == 4 * lg + jj) {
        int row = rw * 16 + 4 * lg + jj;
        float4 A4 = rred[0][row], B4 = rred[1][row];
        float sn = A4.w + B4.w + 1e-8f;
        int g = i * NK + strip * 64 + row;
        SNd[g] = make_float2(__logf(sn), 1.f / sn);
        Rii[g] = make_float4(A4.x + B4.x, A4.y + B4.y, A4.z + B4.z, 0.f);
      }
    }
  }
#pragma unroll
  for (int jj = 0; jj < 4; ++jj) { S1[jj] = 0.f; NP[jj] = 0.f; PE[jj] = 0.f; }

  // ================= CROSS rounds 8..15 =================
  for (int r = 8; r < 16; ++r) {
    int cl[4];
#pragma unroll
    for (int c2 = 0; c2 < 4; ++c2)
      cl[c2] = sel_lab[inxt * NK + (r & 7) * 128 + ch2 * 64 + c2 * 16 + lr];

    const short* bbase = buf[r & 1];
    f32x4 acc[4];
#pragma unroll
    for (int c2 = 0; c2 < 4; ++c2) acc[c2] = f32x4{0.f, 0.f, 0.f, 0.f};
#pragma unroll
    for (int ks = 0; ks < 8; ++ks) {
      int ch = ks * 4 + lg;
      short8 af = afrag[ks];
#pragma unroll
      for (int c2 = 0; c2 < 4; ++c2) {
        int brow = ch2 * 64 + c2 * 16 + lr;
        short8 bf = *(const short8*)(bbase + brow * 256 + ((ch ^ (brow & 15)) << 3));
        acc[c2] = __builtin_amdgcn_mfma_f32_16x16x32_bf16(af, bf, acc[c2], 0, 0, 0);
      }
    }

#pragma unroll
    for (int c2 = 0; c2 < 4; ++c2) {
      const bool cv = (cl[c2] != IGN);
      float cS = 0.f, cN = 0.f, cE = 0.f;
#pragma unroll
      for (int jj = 0; jj < 4; ++jj) {
        float y = acc[c2][jj] - CBIAS;
        float E = fexp2(y);
        float pm = (cv && (rlab[jj] == cl[c2])) ? 1.f : 0.f;
        S1[jj] += pm * y; NP[jj] += pm; PE[jj] += pm * E;
        cS += pm * y; cN += pm; cE += pm * E;
      }
      cS += __shfl_xor(cS, 16); cS += __shfl_xor(cS, 32);
      cN += __shfl_xor(cN, 16); cN += __shfl_xor(cN, 32);
      cE += __shfl_xor(cE, 16); cE += __shfl_xor(cE, 32);
      if (lg == 0) colAcc[rw][ch2 * 64 + c2 * 16 + lr] = make_float4(cS, cN, cE, 0.f);
    }
    ASM_LGKM0; SCHEDB;
    MEMFENCE; BARRIER; MEMFENCE;               // buf free + colAcc visible
    if (rw == 0) {
      int col = ch2 * 64 + lane;
      float4 A4 = colAcc[0][col], B4 = colAcc[1][col];
      float4 C4 = colAcc[2][col], D4 = colAcc[3][col];
      Cp[(i * 16 + strip) * NK + (r & 7) * 128 + col] =
          make_float4(A4.x + B4.x + C4.x + D4.x, A4.y + B4.y + C4.y + D4.y,
                      A4.z + B4.z + C4.z + D4.z, 0.f);
    }
    if (r < 14) { stage_round(r + 2); ASM_VMCNT8; }
    else if (r == 14) { ASM_VMCNT0; }
    if (r < 15) { MEMFENCE; BARRIER; MEMFENCE; }
  }

  // ---- fold cross stats -> Rin ----
#pragma unroll
  for (int jj = 0; jj < 4; ++jj) {
    float a = S1[jj], b4 = NP[jj], c4 = PE[jj];
#pragma unroll
    for (int m = 1; m <= 8; m <<= 1) {
      a += __shfl_xor(a, m); b4 += __shfl_xor(b4, m); c4 += __shfl_xor(c4, m);
    }
    if (lr == 4 * lg + jj) rred[ch2][rw * 16 + 4 * lg + jj] = make_float4(a, b4, c4, 0.f);
  }
  ASM_LGKM0; SCHEDB; MEMFENCE; BARRIER; MEMFENCE;
  if (ch2 == 0) {
#pragma unroll
    for (int jj = 0; jj < 4; ++jj) {
      if (lr == 4 * lg + jj) {
        int row = rw * 16 + 4 * lg + jj;
        float4 A4 = rred[0][row], B4 = rred[1][row];
        Rin[i * NK + strip * 64 + row] =
            make_float4(A4.x + B4.x, A4.y + B4.y, A4.z + B4.z, 0.f);
      }
    }
  }
}

// ---------------------------------------------------------------- kernel 4
// Fold per-row raw sums + per-image aggregate; last block computes the loss.
__global__ __launch_bounds__(1024) void pcl_assemble(const float4* __restrict__ Rii,
                                                     const float4* __restrict__ Rin,
                                                     const float4* __restrict__ Cp,
                                                     const float2* __restrict__ SNd,
                                                     float* __restrict__ Aimg,
                                                     int* __restrict__ counter,
                                                     float* __restrict__ out) {
  const int i = blockIdx.x, t = threadIdx.x, lane = t & 63, w = t >> 6;  // 16 waves
  const int prev = (i + 15) & 15;
  const int r = t;
  float a1n = 0.f, a1c = 0.f, a2n = 0.f, a2c = 0.f;
  {
    float4 rii = Rii[i * NK + r];
    float4 rin = Rin[i * NK + r];
    float2 sn = SNd[i * NK + r];
    float pp_ii = LN2 * rii.x - rii.y * sn.x - sn.y * rii.z;
    float pp_in = LN2 * rin.x - rin.y * sn.x - sn.y * rin.z;
    float np1 = rii.y + rin.y;
    if (np1 > 0.f) { a1n = -(pp_ii + pp_in) / np1; a1c = 1.f; }
    float cs1 = 0.f, cnp = 0.f, cpe = 0.f;
#pragma unroll
    for (int s2 = 0; s2 < 16; ++s2) {
      float4 c = Cp[(prev * 16 + s2) * NK + r];
      cs1 += c.x; cnp += c.y; cpe += c.z;
    }
    float ppc = LN2 * cs1 - cnp * sn.x - sn.y * cpe;
    float np2 = rii.y + cnp;
    if (np2 > 0.f) { a2n = -(pp_ii + ppc) / np2; a2c = 1.f; }
  }
#pragma unroll
  for (int m = 1; m <= 32; m <<= 1) {
    a1n += __shfl_xor(a1n, m); a1c += __shfl_xor(a1c, m);
    a2n += __shfl_xor(a2n, m); a2c += __shfl_xor(a2c, m);
  }
  __shared__ float wred[16][4];
  __shared__ int lastf;
  if (lane == 0) { wred[w][0] = a1n; wred[w][1] = a1c; wred[w][2] = a2n; wred[w][3] = a2c; }
  __syncthreads();
  if (t == 0) {
    float s0 = 0.f, s1 = 0.f, s2 = 0.f, s3 = 0.f;
#pragma unroll
    for (int k2 = 0; k2 < 16; ++k2) {
      s0 += wred[k2][0]; s1 += wred[k2][1]; s2 += wred[k2][2]; s3 += wred[k2][3];
    }
    Aimg[i * 4 + 0] = s0; Aimg[i * 4 + 1] = s1;
    Aimg[i * 4 + 2] = s2; Aimg[i * 4 + 3] = s3;
    __threadfence();
    int old = atomicAdd(counter, 1);
    lastf = (old == NB - 1);
  }
  __syncthreads();
  if (lastf && t < 64) {
    float v = 0.f;
    if (t < NB) {
      int nb = (t + 1) & 15;
      float num = __hip_atomic_load(&Aimg[t * 4 + 0], __ATOMIC_ACQUIRE, __HIP_MEMORY_SCOPE_AGENT)
                + __hip_atomic_load(&Aimg[nb * 4 + 2], __ATOMIC_ACQUIRE, __HIP_MEMORY_SCOPE_AGENT);
      float cnt = __hip_atomic_load(&Aimg[t * 4 + 1], __ATOMIC_ACQUIRE, __HIP_MEMORY_SCOPE_AGENT)
                + __hip_atomic_load(&Aimg[nb * 4 + 3], __ATOMIC_ACQUIRE, __HIP_MEMORY_SCOPE_AGENT);
      v = num / fmaxf(cnt, 1.f);
    }
    v += __shfl_xor(v, 1); v += __shfl_xor(v, 2); v += __shfl_xor(v, 4); v += __shfl_xor(v, 8);
    if (t == 0) out[0] = v / (float)NB;
  }
}

}  // namespace

extern "C" void kernel_launch(void* const* d_in, const int* in_sizes, int n_in,
                              void* d_out, int out_size, void* d_ws, size_t ws_size,
                              hipStream_t stream) {
  (void)in_sizes; (void)n_in; (void)out_size; (void)ws_size;
  const float* feats  = (const float*)d_in[0];
  const int*   labels = (const int*)d_in[1];
  float* out = (float*)d_out;
  char* ws = (char*)d_ws;

  int* sel_lab = (int*)ws;                                       // 64 KB
  int* sel_idx = (int*)(ws + (64 << 10));                        // 64 KB
  unsigned short* SF = (unsigned short*)(ws + (128 << 10));      // 8 MB
  size_t off = (128 << 10) + (size_t)NB * NK * NC * 2;
  float2* SNd = (float2*)(ws + off);  off += (size_t)NB * NK * 8;
  float4* Rii = (float4*)(ws + off);  off += (size_t)NB * NK * 16;
  float4* Rin = (float4*)(ws + off);  off += (size_t)NB * NK * 16;
  float4* Cp  = (float4*)(ws + off);  off += (size_t)NB * 16 * NK * 16;
  float* Aimg = (float*)(ws + off);   off += 64 * sizeof(float);
  int* counter = (int*)(ws + off);

  pcl_sample<<<NB, 256, 0, stream>>>(labels, sel_lab, sel_idx, counter);
  pcl_gather<<<256, 1024, 0, stream>>>(feats, sel_lab, sel_idx, SF);
  pcl_tiles<<<256, 512, 0, stream>>>(SF, sel_lab, SNd, Rii, Rin, Cp);
  pcl_assemble<<<NB, 1024, 0, stream>>>(Rii, Rin, Cp, SNd, Aimg, counter, out);
}

// Round 6
// 87.615 us; speedup vs baseline: 2.8565x; 1.0546x over previous
//
#include <hip/hip_runtime.h>
#include <hip/hip_bf16.h>

namespace {

constexpr int NB  = 16;
constexpr int NC  = 256;
constexpr int NHW = 16384;
constexpr int NK  = 1024;
constexpr int IGN = 255;
constexpr float SCALE = 4.5398164f;   // sqrt((1/0.07) * log2(e))
constexpr float CBIAS = 20.609929f;   // (1/0.07) * log2(e)
constexpr float LN2   = 0.69314718f;

typedef __attribute__((ext_vector_type(8))) short short8;
typedef __attribute__((ext_vector_type(4))) float f32x4;
typedef unsigned int u32;

#define ASM_VMCNT8 asm volatile("s_waitcnt vmcnt(8)" ::: "memory")
#define ASM_VMCNT0 asm volatile("s_waitcnt vmcnt(0)" ::: "memory")
#define ASM_LGKM0  asm volatile("s_waitcnt lgkmcnt(0)" ::: "memory")
#define SCHEDB     __builtin_amdgcn_sched_barrier(0)
#define MEMFENCE   asm volatile("" ::: "memory")
#define BARRIER    __builtin_amdgcn_s_barrier()
#define ACQ_AGENT  __builtin_amdgcn_fence(__ATOMIC_ACQUIRE, "agent")

__device__ __forceinline__ float fexp2(float x) { return __builtin_exp2f(x); }

__device__ __forceinline__ void gl_lds16(const void* g, void* l) {
  __builtin_amdgcn_global_load_lds((const __attribute__((address_space(1))) u32*)g,
                                   (__attribute__((address_space(3))) u32*)l, 16, 0, 0);
}

// ---------------------------------------------------------------- kernel 1
// Stable-priority sampler, 1024 threads. Padded LDS rows (stride 17) for a
// conflict-free per-thread 16-label window. Also zeroes the sync counters.
__global__ __launch_bounds__(1024) void pcl_sample(const int* __restrict__ labels,
                                                   int* __restrict__ sel_lab,
                                                   int* __restrict__ sel_idx,
                                                   int* __restrict__ cnt,
                                                   int* __restrict__ findone) {
  const int b = blockIdx.x, t = threadIdx.x, lane = t & 63, w = t >> 6;  // 16 waves
  if (t == 0) { cnt[b] = 0; if (b == 0) *findone = 0; }
  __shared__ int labL[1024 * 17];     // 68 KB
  __shared__ int wtot[16];

  sel_lab[b * NK + t] = IGN;

  const int* lab = labels + b * NHW;
#pragma unroll
  for (int k = 0; k < 16; ++k) {
    int idx = k * 1024 + t;
    labL[(idx >> 4) * 17 + (idx & 15)] = lab[idx];
  }
  __syncthreads();

  int cfg = 0, cbg = 0;
#pragma unroll
  for (int i = 0; i < 16; ++i) {
    int L = labL[t * 17 + i];
    cfg += (L != IGN && L != 0);
    cbg += (L == 0);
  }
  int packed = cfg | (cbg << 15);
  int incl = packed;
#pragma unroll
  for (int off = 1; off < 64; off <<= 1) {
    int n = __shfl_up(incl, off);
    if (lane >= off) incl += n;
  }
  if (lane == 63) wtot[w] = incl;
  __syncthreads();
  int wb = 0, total = 0;
#pragma unroll
  for (int ww = 0; ww < 16; ++ww) { int v = wtot[ww]; total += v; if (ww < w) wb += v; }
  int excl = incl - packed + wb;
  int rf  = excl & 32767;
  int rbg = (excl >> 15) & 32767;
  const int nfg = total & 32767;
  if (rf < NK || nfg + rbg < NK) {
#pragma unroll
    for (int i = 0; i < 16; ++i) {
      int L = labL[t * 17 + i];
      if (L == IGN) continue;
      if (L != 0) {
        if (rf < NK) { sel_lab[b * NK + rf] = L; sel_idx[b * NK + rf] = t * 16 + i; }
        ++rf;
      } else {
        int s = nfg + rbg;
        if (s < NK) { sel_lab[b * NK + s] = L; sel_idx[b * NK + s] = t * 16 + i; }
        ++rbg;
      }
    }
  }
}

// ---------------------------------------------------------------- kernel 2
// Gather + L2-normalize + pre-scale by SCALE, store bf16. 16 waves/block.
__global__ __launch_bounds__(1024) void pcl_gather(const float* __restrict__ feats,
                                                   const int* __restrict__ sel_lab,
                                                   const int* __restrict__ sel_idx,
                                                   unsigned short* __restrict__ SF) {
  const int b = blockIdx.x >> 4, kb = blockIdx.x & 15;
  const int t = threadIdx.x, s = t & 63, w = t >> 6;
  __shared__ float fbuf[64][257];
  __shared__ float sqs[16][64];
  __shared__ float rn[64];
  const int gk = b * NK + kb * 64 + s;
  const int lb = sel_lab[gk];
  const int p = (lb != IGN) ? sel_idx[gk] : -1;
  const float* fb = feats + (size_t)b * NC * NHW;
  float sq = 0.f;
#pragma unroll
  for (int cc = 0; cc < 16; ++cc) {
    int c = w * 16 + cc;
    float v = (p >= 0) ? fb[(size_t)c * NHW + p] : 0.f;
    fbuf[s][c] = v;
    sq += v * v;
  }
  sqs[w][s] = sq;
  __syncthreads();
  if (t < 64) {
    float tot = 0.f;
#pragma unroll
    for (int k2 = 0; k2 < 16; ++k2) tot += sqs[k2][t];
    rn[t] = SCALE / fmaxf(sqrtf(tot), 1e-12f);
  }
  __syncthreads();
#pragma unroll
  for (int it = 0; it < 2; ++it) {
    int slot = it * 1024 + t;
    int ss = slot >> 5, ch = slot & 31;
    float r = rn[ss];
    short8 v8;
#pragma unroll
    for (int e = 0; e < 8; ++e) {
      float x = fbuf[ss][ch * 8 + e] * r;
      __hip_bfloat16 h = __float2bfloat16(x);
      unsigned short u; __builtin_memcpy(&u, &h, 2);
      v8[e] = (short)u;
    }
    *(short8*)(SF + ((size_t)(b * NK + kb * 64 + ss)) * NC + ch * 8) = v8;
  }
}

// ---------------------------------------------------------------- kernel 3
// Block (i, strip): 64 rows of image i vs 2048 cols (self 1024 + next 1024).
// 8 waves = (rw 0..1: 32-row half) x (ch4 0..3: 32-col quarter). 16x16x32
// MFMA; each B fragment feeds 2 row-tiles. Raw-exp2 epilogue (fold-time
// rescale by 2^-CBIAS); exact self-pair exclusion only in the diag round.
// End-of-block: a1 fold (local), counter dance -> pair fold -> final loss.
__global__ __launch_bounds__(512) void pcl_tiles(
    const unsigned short* __restrict__ SF, const int* __restrict__ sel_lab,
    float2* __restrict__ SNd, float4* __restrict__ Rii, float4* __restrict__ Cp,
    float2* __restrict__ A1arr, float2* __restrict__ Aimg,
    int* __restrict__ cnt, int* __restrict__ findone, float* __restrict__ out) {
  const int id = blockIdx.x;
  const int i = id & 15, strip = id >> 4;
  const int inxt = (i + 1) & 15, iprev = (i + 15) & 15;
  const int t = threadIdx.x, lane = t & 63, w = t >> 6;
  const int rw = w & 1, ch4 = w >> 1;
  const int lg = lane >> 4, lr = lane & 15;
  const float SFAC = __builtin_exp2f(-CBIAS);

  __shared__ short buf[2][128 * 256];          // 128 KB
  __shared__ float4 colAcc[2][128];            // 4 KB
  __shared__ float4 rredS[4][64];              // 4 KB
  __shared__ float4 rredX[4][64];              // 4 KB
  __shared__ float2 fold2[8];
  __shared__ int fA, fB;

  const unsigned short* SFrow = SF + (size_t)i * (NK * NC) + strip * 64 * NC;

  auto stage_round = [&](int rr) {
    const unsigned short* base =
        SF + (size_t)((rr < 8) ? i : inxt) * (NK * NC) + ((rr & 7) * 128) * NC;
    short* dst = buf[rr & 1];
#pragma unroll
    for (int it = 0; it < 8; ++it) {
      int n = it * 512 + t, row = n >> 5, ch = n & 31;
      gl_lds16(base + row * NC + ((ch ^ (row & 15)) << 3), dst + (size_t)n * 8);
    }
  };

  // ---- prologue ----
#pragma unroll
  for (int it = 0; it < 4; ++it) {
    int n = it * 512 + t, row = n >> 5, ch = n & 31;
    gl_lds16(SFrow + row * NC + ((ch ^ (row & 15)) << 3), buf[0] + (size_t)n * 8);
  }
  ASM_VMCNT0; MEMFENCE; BARRIER; MEMFENCE;

  short8 afrag[2][8];
#pragma unroll
  for (int rt = 0; rt < 2; ++rt) {
    const int arow = rw * 32 + rt * 16 + lr;
#pragma unroll
    for (int ks = 0; ks < 8; ++ks) {
      int ch = ks * 4 + lg;
      afrag[rt][ks] = *(const short8*)(buf[0] + arow * 256 + ((ch ^ (arow & 15)) << 3));
    }
  }
  ASM_LGKM0; SCHEDB; MEMFENCE; BARRIER; MEMFENCE;   // buf0 free

  stage_round(0);
  stage_round(1);

  int rlab[2][4];
#pragma unroll
  for (int rt = 0; rt < 2; ++rt)
#pragma unroll
    for (int jj = 0; jj < 4; ++jj) {
      int L = sel_lab[i * NK + strip * 64 + rw * 32 + rt * 16 + 4 * lg + jj];
      rlab[rt][jj] = (L == IGN) ? -1 : L;
    }

  ASM_VMCNT8; MEMFENCE; BARRIER; MEMFENCE;     // round 0 ready

  float SA[2][4], NPr[2][4], PEr[2][4], ETr[2][4];
#pragma unroll
  for (int rt = 0; rt < 2; ++rt)
#pragma unroll
    for (int jj = 0; jj < 4; ++jj) { SA[rt][jj] = 0.f; NPr[rt][jj] = 0.f; PEr[rt][jj] = 0.f; ETr[rt][jj] = 0.f; }

  const int rs = strip >> 1;                    // diag round
  const bool dwave = ((ch4 >> 1) == (strip & 1));

  // ================= SELF rounds 0..7 =================
  for (int r = 0; r < 8; ++r) {
    int cl[2]; float cvf[2];
#pragma unroll
    for (int c2 = 0; c2 < 2; ++c2) {
      int L = sel_lab[i * NK + r * 128 + ch4 * 32 + c2 * 16 + lr];
      cl[c2] = (L == IGN) ? -2 : L;
      cvf[c2] = (L == IGN) ? 0.f : 1.f;
    }

    const short* bb = buf[r & 1];
    f32x4 acc[2][2];
#pragma unroll
    for (int rt = 0; rt < 2; ++rt)
#pragma unroll
      for (int c2 = 0; c2 < 2; ++c2) acc[rt][c2] = f32x4{0.f, 0.f, 0.f, 0.f};
#pragma unroll
    for (int ks = 0; ks < 8; ++ks) {
      int ch = ks * 4 + lg;
      short8 b0, b1;
      {
        int br0 = ch4 * 32 + lr, br1 = ch4 * 32 + 16 + lr;
        b0 = *(const short8*)(bb + br0 * 256 + ((ch ^ (br0 & 15)) << 3));
        b1 = *(const short8*)(bb + br1 * 256 + ((ch ^ (br1 & 15)) << 3));
      }
      acc[0][0] = __builtin_amdgcn_mfma_f32_16x16x32_bf16(afrag[0][ks], b0, acc[0][0], 0, 0, 0);
      acc[0][1] = __builtin_amdgcn_mfma_f32_16x16x32_bf16(afrag[0][ks], b1, acc[0][1], 0, 0, 0);
      acc[1][0] = __builtin_amdgcn_mfma_f32_16x16x32_bf16(afrag[1][ks], b0, acc[1][0], 0, 0, 0);
      acc[1][1] = __builtin_amdgcn_mfma_f32_16x16x32_bf16(afrag[1][ks], b1, acc[1][1], 0, 0, 0);
    }

    const bool isdiag = (r == rs) && dwave;
#pragma unroll
    for (int rt = 0; rt < 2; ++rt)
#pragma unroll
      for (int c2 = 0; c2 < 2; ++c2) {
        const int clc = cl[c2]; const float cvc = cvf[c2];
        const int gc = r * 128 + ch4 * 32 + c2 * 16 + lr;
        const int grb = strip * 64 + rw * 32 + rt * 16 + 4 * lg;
#pragma unroll
        for (int jj = 0; jj < 4; ++jj) {
          float a = acc[rt][c2][jj];
          float E = fexp2(a);
          float Ev = cvc * E;
          float pm = (rlab[rt][jj] == clc) ? 1.f : 0.f;
          if (isdiag) {
            bool ok = (grb + jj) != gc;
            pm = ok ? pm : 0.f;
            Ev = ok ? Ev : 0.f;
          }
          SA[rt][jj] += pm * a; NPr[rt][jj] += pm;
          PEr[rt][jj] += pm * Ev; ETr[rt][jj] += Ev;
        }
      }

    MEMFENCE; BARRIER; MEMFENCE;
    stage_round(r + 2);
    ASM_VMCNT8;
    MEMFENCE; BARRIER; MEMFENCE;
  }

  // ---- self fold -> rredS ----
#pragma unroll
  for (int rt = 0; rt < 2; ++rt)
#pragma unroll
    for (int jj = 0; jj < 4; ++jj) {
      float a = SA[rt][jj], b4 = NPr[rt][jj], c4 = PEr[rt][jj], d4 = ETr[rt][jj];
#pragma unroll
      for (int m = 1; m <= 8; m <<= 1) {
        a += __shfl_xor(a, m); b4 += __shfl_xor(b4, m);
        c4 += __shfl_xor(c4, m); d4 += __shfl_xor(d4, m);
      }
      if (lr == 0) rredS[ch4][rw * 32 + rt * 16 + 4 * lg + jj] = make_float4(a, b4, c4, d4);
    }

  float SX[2][4], NX[2][4], PX[2][4];
#pragma unroll
  for (int rt = 0; rt < 2; ++rt)
#pragma unroll
    for (int jj = 0; jj < 4; ++jj) { SX[rt][jj] = 0.f; NX[rt][jj] = 0.f; PX[rt][jj] = 0.f; }

  // ================= CROSS rounds 8..15 =================
  for (int r = 8; r < 16; ++r) {
    int cl[2];
#pragma unroll
    for (int c2 = 0; c2 < 2; ++c2) {
      int L = sel_lab[inxt * NK + (r & 7) * 128 + ch4 * 32 + c2 * 16 + lr];
      cl[c2] = (L == IGN) ? -2 : L;
    }

    const short* bb = buf[r & 1];
    f32x4 acc[2][2];
#pragma unroll
    for (int rt = 0; rt < 2; ++rt)
#pragma unroll
      for (int c2 = 0; c2 < 2; ++c2) acc[rt][c2] = f32x4{0.f, 0.f, 0.f, 0.f};
#pragma unroll
    for (int ks = 0; ks < 8; ++ks) {
      int ch = ks * 4 + lg;
      short8 b0, b1;
      {
        int br0 = ch4 * 32 + lr, br1 = ch4 * 32 + 16 + lr;
        b0 = *(const short8*)(bb + br0 * 256 + ((ch ^ (br0 & 15)) << 3));
        b1 = *(const short8*)(bb + br1 * 256 + ((ch ^ (br1 & 15)) << 3));
      }
      acc[0][0] = __builtin_amdgcn_mfma_f32_16x16x32_bf16(afrag[0][ks], b0, acc[0][0], 0, 0, 0);
      acc[0][1] = __builtin_amdgcn_mfma_f32_16x16x32_bf16(afrag[0][ks], b1, acc[0][1], 0, 0, 0);
      acc[1][0] = __builtin_amdgcn_mfma_f32_16x16x32_bf16(afrag[1][ks], b0, acc[1][0], 0, 0, 0);
      acc[1][1] = __builtin_amdgcn_mfma_f32_16x16x32_bf16(afrag[1][ks], b1, acc[1][1], 0, 0, 0);
    }

    float cS[2], cN[2], cE[2];
#pragma unroll
    for (int c2 = 0; c2 < 2; ++c2) { cS[c2] = 0.f; cN[c2] = 0.f; cE[c2] = 0.f; }
#pragma unroll
    for (int rt = 0; rt < 2; ++rt)
#pragma unroll
      for (int c2 = 0; c2 < 2; ++c2) {
        const int clc = cl[c2];
#pragma unroll
        for (int jj = 0; jj < 4; ++jj) {
          float a = acc[rt][c2][jj];
          float E = fexp2(a);
          float pm = (rlab[rt][jj] == clc) ? 1.f : 0.f;
          float pa = pm * a, pe = pm * E;
          SX[rt][jj] += pa; NX[rt][jj] += pm; PX[rt][jj] += pe;
          cS[c2] += pa; cN[c2] += pm; cE[c2] += pe;
        }
      }
#pragma unroll
    for (int c2 = 0; c2 < 2; ++c2) {
      cS[c2] += __shfl_xor(cS[c2], 16); cS[c2] += __shfl_xor(cS[c2], 32);
      cN[c2] += __shfl_xor(cN[c2], 16); cN[c2] += __shfl_xor(cN[c2], 32);
      cE[c2] += __shfl_xor(cE[c2], 16); cE[c2] += __shfl_xor(cE[c2], 32);
      if (lg == 0) colAcc[rw][ch4 * 32 + c2 * 16 + lr] = make_float4(cS[c2], cN[c2], cE[c2], 0.f);
    }
    ASM_LGKM0; SCHEDB;
    MEMFENCE; BARRIER; MEMFENCE;
    if (rw == 1 && lg == 0) {
#pragma unroll
      for (int c2 = 0; c2 < 2; ++c2) {
        int col = ch4 * 32 + c2 * 16 + lr;
        float4 o = colAcc[0][col];
        Cp[(i * 16 + strip) * NK + (r & 7) * 128 + col] =
            make_float4(cS[c2] + o.x, cN[c2] + o.y, (cE[c2] + o.z) * SFAC, 0.f);
      }
    }
    if (r < 14) { stage_round(r + 2); ASM_VMCNT8; MEMFENCE; BARRIER; MEMFENCE; }
    else if (r == 14) { ASM_VMCNT0; MEMFENCE; BARRIER; MEMFENCE; }
  }

  // ---- cross fold -> rredX ----
#pragma unroll
  for (int rt = 0; rt < 2; ++rt)
#pragma unroll
    for (int jj = 0; jj < 4; ++jj) {
      float a = SX[rt][jj], b4 = NX[rt][jj], c4 = PX[rt][jj];
#pragma unroll
      for (int m = 1; m <= 8; m <<= 1) {
        a += __shfl_xor(a, m); b4 += __shfl_xor(b4, m); c4 += __shfl_xor(c4, m);
      }
      if (lr == 0) rredX[ch4][rw * 32 + rt * 16 + 4 * lg + jj] = make_float4(a, b4, c4, 0.f);
    }
  __syncthreads();

  // ---- per-row pass: SNd/Rii writes + local a1 ----
  if (t < 64) {
    float4 sS = rredS[0][t], sX = rredX[0][t];
#pragma unroll
    for (int c4 = 1; c4 < 4; ++c4) {
      float4 u = rredS[c4][t], v = rredX[c4][t];
      sS.x += u.x; sS.y += u.y; sS.z += u.z; sS.w += u.w;
      sX.x += v.x; sX.y += v.y; sX.z += v.z;
    }
    float SNL = sS.w - sS.z;
    float SN = SNL * SFAC + 1e-8f;
    float LSN = __logf(SN), rSN = 1.f / SN;
    int g = i * NK + strip * 64 + t;
    SNd[g] = make_float2(LSN, rSN);
    Rii[g] = make_float4(sS.x, sS.y, sS.z * SFAC, 0.f);
    float pps = LN2 * (sS.x - CBIAS * sS.y) - sS.y * LSN - rSN * (sS.z * SFAC);
    float ppx = LN2 * (sX.x - CBIAS * sX.y) - sX.y * LSN - rSN * (sX.z * SFAC);
    float np1 = sS.y + sX.y;
    float an = 0.f, ac = 0.f;
    if (np1 > 0.f) { an = -(pps + ppx) / np1; ac = 1.f; }
#pragma unroll
    for (int m = 1; m <= 32; m <<= 1) { an += __shfl_xor(an, m); ac += __shfl_xor(ac, m); }
    if (t == 0) A1arr[i * 16 + strip] = make_float2(an, ac);
  }
  __syncthreads();

  // ---- counter dance ----
  if (t == 0) {
    __threadfence();
    int o1 = atomicAdd(&cnt[i], 1);
    int o2 = atomicAdd(&cnt[iprev], 1);
    fA = (o1 == 31); fB = (o2 == 31);
  }
  __syncthreads();

  auto pair_fold = [&](int p) {
    const int q = (p + 1) & 15;
    ACQ_AGENT;
    float an = 0.f, ac = 0.f;
    for (int r2 = t; r2 < NK; r2 += 512) {
      float4 rii = Rii[q * NK + r2];
      float2 sn = SNd[q * NK + r2];
      float cs = 0.f, cn = 0.f, ce = 0.f;
#pragma unroll
      for (int s2 = 0; s2 < 16; ++s2) {
        float4 c = Cp[(p * 16 + s2) * NK + r2];
        cs += c.x; cn += c.y; ce += c.z;
      }
      float ppc = LN2 * (cs - CBIAS * cn) - cn * sn.x - sn.y * ce;
      float ppi = LN2 * (rii.x - CBIAS * rii.y) - rii.y * sn.x - sn.y * rii.z;
      float np2 = rii.y + cn;
      if (np2 > 0.f) { an -= (ppi + ppc) / np2; ac += 1.f; }
    }
#pragma unroll
    for (int m = 1; m <= 32; m <<= 1) { an += __shfl_xor(an, m); ac += __shfl_xor(ac, m); }
    if (lane == 0) fold2[w] = make_float2(an, ac);
    __syncthreads();
    if (t == 0) {
      float a2n = 0.f, a2c = 0.f;
#pragma unroll
      for (int k2 = 0; k2 < 8; ++k2) { a2n += fold2[k2].x; a2c += fold2[k2].y; }
      float a1n = 0.f, a1c = 0.f;
#pragma unroll
      for (int s2 = 0; s2 < 16; ++s2) {
        float2 a = A1arr[q * 16 + s2];
        a1n += a.x; a1c += a.y;
      }
      Aimg[q] = make_float2(a1n + a2n, a1c + a2c);
      __threadfence();
      int f = atomicAdd(findone, 1);
      if (f == NB - 1) {
        ACQ_AGENT;
        float v = 0.f;
#pragma unroll
        for (int im = 0; im < NB; ++im) {
          float2 gg = Aimg[im];
          v += gg.x / fmaxf(gg.y, 1.f);
        }
        out[0] = v / (float)NB;
      }
    }
    __syncthreads();
  };

  if (fA) pair_fold(i);
  if (fB) pair_fold(iprev);
}

}  // namespace

extern "C" void kernel_launch(void* const* d_in, const int* in_sizes, int n_in,
                              void* d_out, int out_size, void* d_ws, size_t ws_size,
                              hipStream_t stream) {
  (void)in_sizes; (void)n_in; (void)out_size; (void)ws_size;
  const float* feats  = (const float*)d_in[0];
  const int*   labels = (const int*)d_in[1];
  float* out = (float*)d_out;
  char* ws = (char*)d_ws;

  int* sel_lab = (int*)ws;                                       // 64 KB
  int* sel_idx = (int*)(ws + (64 << 10));                        // 64 KB
  unsigned short* SF = (unsigned short*)(ws + (128 << 10));      // 8 MB
  size_t off = (128 << 10) + (size_t)NB * NK * NC * 2;
  float2* SNd = (float2*)(ws + off);  off += (size_t)NB * NK * 8;      // 128 KB
  float4* Rii = (float4*)(ws + off);  off += (size_t)NB * NK * 16;     // 256 KB
  float4* Cp  = (float4*)(ws + off);  off += (size_t)NB * 16 * NK * 16; // 4 MB
  float2* A1arr = (float2*)(ws + off); off += (size_t)NB * 16 * 8;
  float2* Aimg = (float2*)(ws + off);  off += NB * 8;
  int* cnt = (int*)(ws + off);         off += 16 * 4;
  int* findone = (int*)(ws + off);

  pcl_sample<<<NB, 1024, 0, stream>>>(labels, sel_lab, sel_idx, cnt, findone);
  pcl_gather<<<256, 1024, 0, stream>>>(feats, sel_lab, sel_idx, SF);
  pcl_tiles<<<256, 512, 0, stream>>>(SF, sel_lab, SNd, Rii, Cp, A1arr, Aimg,
                                     cnt, findone, out);
}